// Round 1
// baseline (3355.929 us; speedup 1.0000x reference)
//
#include <hip/hip_runtime.h>
#include <math.h>
#include <float.h>

#define NN 50000
#define NE 800000

// ---------------- setup kernels ----------------

__global__ void k_count(const int* __restrict__ dst, int* __restrict__ cnt){
  int e = blockIdx.x*blockDim.x + threadIdx.x;
  if (e < NE) atomicAdd(&cnt[dst[e]], 1);
}

__global__ void k_scan_part(const int* __restrict__ cnt, int* __restrict__ offs, int* __restrict__ totals){
  __shared__ int sh[1024];
  int t = threadIdx.x, i = blockIdx.x*1024 + t;
  int v = (i < NN) ? cnt[i] : 0;
  sh[t] = v; __syncthreads();
  for (int off = 1; off < 1024; off <<= 1){
    int x = (t >= off) ? sh[t-off] : 0;
    __syncthreads();
    sh[t] += x;
    __syncthreads();
  }
  if (i < NN) offs[i] = sh[t] - v;     // exclusive within block
  if (t == 1023) totals[blockIdx.x] = sh[t];
}

__global__ void k_scan_tops(int* totals, int nb){
  if (threadIdx.x == 0){
    int acc = 0;
    for (int i = 0; i < nb; i++){ int v = totals[i]; totals[i] = acc; acc += v; }
  }
}

__global__ void k_scan_add(int* __restrict__ offs, const int* __restrict__ totals, int* __restrict__ cursor){
  int i = blockIdx.x*blockDim.x + threadIdx.x;
  if (i < NN){
    int v = offs[i] + totals[i >> 10];
    offs[i] = v;
    cursor[i] = v;
  } else if (i == NN){
    offs[NN] = NE;
  }
}

__global__ void k_scatter(const int* __restrict__ ei, int* __restrict__ cursor,
                          int* __restrict__ ssrc, int* __restrict__ seid){
  int e = blockIdx.x*blockDim.x + threadIdx.x;
  if (e >= NE) return;
  int d = ei[NE + e];
  int p = atomicAdd(&cursor[d], 1);
  ssrc[p] = ei[e];
  seid[p] = e;
}

__global__ void k_sumlog(const int* __restrict__ cnt, float* __restrict__ sumlog){
  __shared__ float sh[256];
  int t = threadIdx.x;
  float s = 0.f;
  for (int i = blockIdx.x*256 + t; i < NN; i += gridDim.x*256)
    s += logf((float)cnt[i] + 1.f);
  sh[t] = s; __syncthreads();
  for (int o = 128; o > 0; o >>= 1){ if (t < o) sh[t] += sh[t+o]; __syncthreads(); }
  if (t == 0) atomicAdd(sumlog, sh[0]);
}

__global__ void k_rscale(const int* __restrict__ cnt, const float* __restrict__ sumlog,
                         float* __restrict__ r1, float* __restrict__ r2){
  int i = blockIdx.x*blockDim.x + threadIdx.x;
  if (i >= NN) return;
  float avg = sumlog[0] / (float)NN;
  float logd = logf(fmaxf((float)cnt[i], 1.f) + 1.f);
  r1[i] = logd / avg;
  r2[i] = avg / logd;
}

// ---------------- per-layer weight prep ----------------

// WeL = we @ wp_bot  (13 x fi), bL = bp + be @ wp_bot
__global__ void k_prep_edge(const float* __restrict__ we, const float* __restrict__ be,
                            const float* __restrict__ wp, const float* __restrict__ bp,
                            float* __restrict__ WeL, float* __restrict__ bL, int fi){
  int f = blockIdx.x*blockDim.x + threadIdx.x;
  if (f >= fi) return;
  const float* wpb = wp + (size_t)2*fi*fi;
  for (int r = 0; r < 13; r++){
    float s = 0.f;
    for (int j = 0; j < fi; j++) s += we[r*fi + j] * wpb[(size_t)j*fi + f];
    WeL[r*fi + f] = s;
  }
  float s = bp[f];
  for (int j = 0; j < fi; j++) s += be[j] * wpb[(size_t)j*fi + f];
  bL[f] = s;
}

// Wol = wo @ wl   (13fi x fo);  grid = 13fi blocks of fo threads
__global__ void k_prep_wol(const float* __restrict__ wo, const float* __restrict__ wl,
                           float* __restrict__ Wol, int fo){
  int o = threadIdx.x;
  int k = blockIdx.x;
  float s = 0.f;
  for (int j = 0; j < fo; j++) s += wo[(size_t)k*fo + j] * wl[(size_t)j*fo + o];
  Wol[(size_t)k*fo + o] = s;
}

// ---------------- GEMMs ----------------
// Tiled fp32 GEMM: C[M,Nout] = A[M,K] @ B[K,Nout] (+bias). K % 32 == 0.
__global__ __launch_bounds__(256) void k_gemm(int M, int Nout, int K,
    const float* __restrict__ A, int lda, const float* __restrict__ B, int ldb,
    float* __restrict__ C, int ldc, const float* __restrict__ bias){
  __shared__ float As[32][65];
  __shared__ float Bs[32][65];
  int tid = threadIdx.x, tx = tid & 15, ty = tid >> 4;
  int row0 = blockIdx.x*64, col0 = blockIdx.y*64;
  float acc[4][4] = {};
  for (int k0 = 0; k0 < K; k0 += 32){
    #pragma unroll
    for (int i = 0; i < 8; i++){
      int k = tid & 31, m = i*8 + (tid >> 5);
      int gr = row0 + m;
      As[k][m] = (gr < M) ? A[(size_t)gr*lda + k0 + k] : 0.f;
    }
    #pragma unroll
    for (int i = 0; i < 8; i++){
      int n = tid & 63, k = i*4 + (tid >> 6);
      int gc = col0 + n;
      Bs[k][n] = (gc < Nout) ? B[(size_t)(k0 + k)*ldb + gc] : 0.f;
    }
    __syncthreads();
    #pragma unroll
    for (int kk = 0; kk < 32; kk++){
      float a[4], b[4];
      #pragma unroll
      for (int i = 0; i < 4; i++) a[i] = As[kk][ty*4 + i];
      #pragma unroll
      for (int j = 0; j < 4; j++) b[j] = Bs[kk][tx*4 + j];
      #pragma unroll
      for (int i = 0; i < 4; i++)
        #pragma unroll
        for (int j = 0; j < 4; j++) acc[i][j] += a[i]*b[j];
    }
    __syncthreads();
  }
  for (int i = 0; i < 4; i++){
    int gr = row0 + ty*4 + i;
    if (gr >= M) continue;
    for (int j = 0; j < 4; j++){
      int gc = col0 + tx*4 + j;
      if (gc < Nout) C[(size_t)gr*ldc + gc] = acc[i][j] + (bias ? bias[gc] : 0.f);
    }
  }
}

// Same GEMM but A is generated on the fly: z = [x | mean mn mx std | r1*(...) | r2*(...)]
__global__ __launch_bounds__(256) void k_gemm_z(int M, int Nout, int K,
    const float* __restrict__ x, const float* __restrict__ a0, const float* __restrict__ a1,
    const float* __restrict__ a2, const float* __restrict__ a3,
    const float* __restrict__ r1, const float* __restrict__ r2, int FI,
    const float* __restrict__ B, int ldb, float* __restrict__ C, int ldc){
  __shared__ float As[32][65];
  __shared__ float Bs[32][65];
  int tid = threadIdx.x, tx = tid & 15, ty = tid >> 4;
  int row0 = blockIdx.x*64, col0 = blockIdx.y*64;
  float acc[4][4] = {};
  const float* Pt[5] = {x, a0, a1, a2, a3};
  for (int k0 = 0; k0 < K; k0 += 32){
    int kb = k0 / FI;                       // FI % 32 == 0 -> uniform per tile
    int pi = (kb == 0) ? 0 : ((kb - 1) & 3) + 1;
    int sm = (kb == 0) ? 0 : ((kb - 1) >> 2);
    const float* P = Pt[pi];
    int j0 = k0 - kb*FI;
    #pragma unroll
    for (int i = 0; i < 8; i++){
      int k = tid & 31, m = i*8 + (tid >> 5);
      int gr = row0 + m;
      float v = 0.f;
      if (gr < M){
        v = P[(size_t)gr*FI + j0 + k];
        if (sm == 1) v *= r1[gr];
        else if (sm == 2) v *= r2[gr];
      }
      As[k][m] = v;
    }
    #pragma unroll
    for (int i = 0; i < 8; i++){
      int n = tid & 63, k = i*4 + (tid >> 6);
      int gc = col0 + n;
      Bs[k][n] = (gc < Nout) ? B[(size_t)(k0 + k)*ldb + gc] : 0.f;
    }
    __syncthreads();
    #pragma unroll
    for (int kk = 0; kk < 32; kk++){
      float a[4], b[4];
      #pragma unroll
      for (int i = 0; i < 4; i++) a[i] = As[kk][ty*4 + i];
      #pragma unroll
      for (int j = 0; j < 4; j++) b[j] = Bs[kk][tx*4 + j];
      #pragma unroll
      for (int i = 0; i < 4; i++)
        #pragma unroll
        for (int j = 0; j < 4; j++) acc[i][j] += a[i]*b[j];
    }
    __syncthreads();
  }
  for (int i = 0; i < 4; i++){
    int gr = row0 + ty*4 + i;
    if (gr >= M) continue;
    for (int j = 0; j < 4; j++){
      int gc = col0 + tx*4 + j;
      if (gc < Nout) C[(size_t)gr*ldc + gc] = acc[i][j];
    }
  }
}

// ---------------- aggregation (CSR, per node) ----------------
__global__ void k_aggregate(const int* __restrict__ offs, const int* __restrict__ ssrc,
    const int* __restrict__ seid, const float* __restrict__ edge_attr,
    const float* __restrict__ t_d, const float* __restrict__ t_s,
    const float* __restrict__ WeL, const float* __restrict__ bL,
    float* __restrict__ mean, float* __restrict__ mn, float* __restrict__ mx,
    float* __restrict__ stdv, int fi){
  extern __shared__ float sh[];   // [13*fi] WeL then [fi] bL
  int tid = threadIdx.x;
  int npb = blockDim.x / fi;
  for (int i = tid; i < 14*fi; i += blockDim.x)
    sh[i] = (i < 13*fi) ? WeL[i] : bL[i - 13*fi];
  __syncthreads();
  int local = tid / fi, f = tid % fi;
  int n = blockIdx.x * npb + local;
  if (n >= NN) return;
  float base = t_d[(size_t)n*fi + f] + sh[13*fi + f];
  int e0 = offs[n], e1 = offs[n+1];
  float s = 0.f, s2 = 0.f, vmn = FLT_MAX, vmx = -FLT_MAX;
  for (int p = e0; p < e1; p++){
    int src = ssrc[p], eid = seid[p];
    const float* ea = edge_attr + (size_t)eid*13;
    float m = base + t_s[(size_t)src*fi + f];
    #pragma unroll
    for (int r = 0; r < 13; r++) m += ea[r] * sh[r*fi + f];
    s += m; s2 += m*m;
    vmn = fminf(vmn, m); vmx = fmaxf(vmx, m);
  }
  int c = e1 - e0;
  float denom = fmaxf((float)c, 1.f);
  float me = s/denom, me2 = s2/denom;
  float sd = sqrtf(fmaxf(me2 - me*me, 0.f) + 1e-5f);
  size_t o = (size_t)n*fi + f;
  mean[o] = me;
  stdv[o] = sd;
  mn[o] = (c > 0) ? vmn : 0.f;
  mx[o] = (c > 0) ? vmx : 0.f;
}

// ---------------- BatchNorm ----------------
__global__ void k_bn_reduce(const float* __restrict__ x, float* __restrict__ sums, int fo, int rows){
  __shared__ float sh[512];
  int tid = threadIdx.x;
  int col = tid % fo, grp = tid / fo, ngrp = 256 / fo;
  float s = 0.f, s2 = 0.f;
  int r0 = blockIdx.x * rows;
  int rend = min(r0 + rows, NN);
  for (int r = r0 + grp; r < rend; r += ngrp){
    float v = x[(size_t)r*fo + col];
    s += v; s2 += v*v;
  }
  sh[tid] = s; sh[256 + tid] = s2;
  __syncthreads();
  if (grp == 0){
    for (int g = 1; g < ngrp; g++){ s += sh[g*fo + col]; s2 += sh[256 + g*fo + col]; }
    atomicAdd(&sums[col], s);
    atomicAdd(&sums[fo + col], s2);
  }
}

__global__ void k_bn_apply(float* __restrict__ x, const float* __restrict__ sums,
                           const float* __restrict__ g, const float* __restrict__ b,
                           int fo, int total){
  int i = blockIdx.x*blockDim.x + threadIdx.x;
  if (i >= total) return;
  int col = i % fo;
  float mu = sums[col] / (float)NN;
  float var = sums[fo + col] / (float)NN - mu*mu;
  float v = (x[i] - mu) * rsqrtf(var + 1e-5f) * g[col] + b[col];
  x[i] = fmaxf(v, 0.f);
}

// ---------------- host ----------------
extern "C" void kernel_launch(void* const* d_in, const int* in_sizes, int n_in,
                              void* d_out, int out_size, void* d_ws, size_t ws_size,
                              hipStream_t stream){
  const float* x0 = (const float*)d_in[0];
  const int*   ei = (const int*)d_in[1];
  const float* ea = (const float*)d_in[2];
  const float* W[35];
  for (int i = 0; i < 35; i++) W[i] = (const float*)d_in[i];
  const float* wc = W[33];
  const float* bc = W[34];

  char* w = (char*)d_ws;
  auto alloc = [&](size_t bytes)->void*{
    void* p = (void*)w; w += (bytes + 255) & ~(size_t)255; return p;
  };
  int* cnt    = (int*)alloc((size_t)NN*4);
  int* offs   = (int*)alloc((size_t)(NN+1)*4);
  int* cursor = (int*)alloc((size_t)NN*4);
  int* totals = (int*)alloc(64*4);
  int* ssrc   = (int*)alloc((size_t)NE*4);
  int* seid   = (int*)alloc((size_t)NE*4);
  float* sumlog = (float*)alloc(256);
  float* r1   = (float*)alloc((size_t)NN*4);
  float* r2   = (float*)alloc((size_t)NN*4);
  float* bns  = (float*)alloc(512*4);
  float* WeL  = (float*)alloc(13*128*4);
  float* bL   = (float*)alloc(128*4);
  float* Wol  = (float*)alloc((size_t)1664*256*4);
  float* agg[4];
  for (int a = 0; a < 4; a++) agg[a] = (float*)alloc((size_t)NN*128*4);
  float* bufA = (float*)alloc((size_t)NN*256*4);
  float* bufB = (float*)alloc((size_t)NN*256*4);

  hipMemsetAsync(cnt, 0, (size_t)NN*4, stream);
  hipMemsetAsync(sumlog, 0, 4, stream);
  k_count<<<(NE+255)/256, 256, 0, stream>>>(ei + NE, cnt);
  k_scan_part<<<49, 1024, 0, stream>>>(cnt, offs, totals);
  k_scan_tops<<<1, 64, 0, stream>>>(totals, 49);
  k_scan_add<<<(NN+256)/256, 256, 0, stream>>>(offs, totals, cursor);
  k_scatter<<<(NE+255)/256, 256, 0, stream>>>(ei, cursor, ssrc, seid);
  k_sumlog<<<256, 256, 0, stream>>>(cnt, sumlog);
  k_rscale<<<(NN+255)/256, 256, 0, stream>>>(cnt, sumlog, r1, r2);

  const float* xin = x0;
  float* xout = bufB;
  const int fis[3] = {32, 64, 128};
  for (int l = 0; l < 3; l++){
    int fi = fis[l], fo = 2*fi;
    const float* we = W[3+10*l+0], *be = W[3+10*l+1];
    const float* wp = W[3+10*l+2], *bp = W[3+10*l+3];
    const float* wo = W[3+10*l+4];
    const float* wl = W[3+10*l+6];
    const float* g  = W[3+10*l+8], *bb = W[3+10*l+9];

    float* t_d = xout;                       // [NN, fi] — dead before xout is rewritten
    float* t_s = xout + (size_t)NN*fi;       // [NN, fi]

    k_prep_edge<<<(fi+127)/128, 128, 0, stream>>>(we, be, wp, bp, WeL, bL, fi);
    k_prep_wol<<<13*fi, fo, 0, stream>>>(wo, wl, Wol, fo);

    dim3 gt((NN+63)/64, (fi+63)/64);
    k_gemm<<<gt, 256, 0, stream>>>(NN, fi, fi, xin, fi, wp, fi, t_d, fi, nullptr);
    k_gemm<<<gt, 256, 0, stream>>>(NN, fi, fi, xin, fi, wp + (size_t)fi*fi, fi, t_s, fi, nullptr);

    int bs = (fi < 64) ? 64 : fi;
    int npb = bs / fi;
    k_aggregate<<<(NN+npb-1)/npb, bs, 14*fi*4, stream>>>(offs, ssrc, seid, ea, t_d, t_s,
        WeL, bL, agg[0], agg[1], agg[2], agg[3], fi);

    dim3 gz((NN+63)/64, (fo+63)/64);
    k_gemm_z<<<gz, 256, 0, stream>>>(NN, fo, 13*fi, xin, agg[0], agg[1], agg[2], agg[3],
        r1, r2, fi, Wol, fo, xout, fo);

    hipMemsetAsync(bns, 0, (size_t)2*fo*4, stream);
    k_bn_reduce<<<256, 256, 0, stream>>>(xout, bns, fo, (NN+255)/256);
    k_bn_apply<<<((NN*fo)+255)/256, 256, 0, stream>>>(xout, bns, g, bb, fo, NN*fo);

    xin = xout;
    xout = (xout == bufB) ? bufA : bufB;
  }

  dim3 gc((NN+63)/64, 1);
  k_gemm<<<gc, 256, 0, stream>>>(NN, 10, 256, xin, 256, wc, 10, (float*)d_out, 10, bc);
}

// Round 2
// 1524.968 us; speedup vs baseline: 2.2007x; 2.2007x over previous
//
#include <hip/hip_runtime.h>
#include <math.h>
#include <float.h>

#define NN 50000
#define NE 800000

typedef __attribute__((ext_vector_type(8))) short bf16x8;
typedef __attribute__((ext_vector_type(4))) float f32x4;

__device__ inline short f2bf(float f){
  union { float f; unsigned u; } v; v.f = f;
  unsigned u = v.u + 0x7FFFu + ((v.u >> 16) & 1u);
  return (short)(u >> 16);
}

// ---------------- setup kernels ----------------

__global__ void k_count(const int* __restrict__ dst, int* __restrict__ cnt){
  int e = blockIdx.x*blockDim.x + threadIdx.x;
  if (e < NE) atomicAdd(&cnt[dst[e]], 1);
}

__global__ void k_scan_part(const int* __restrict__ cnt, int* __restrict__ offs, int* __restrict__ totals){
  __shared__ int sh[1024];
  int t = threadIdx.x, i = blockIdx.x*1024 + t;
  int v = (i < NN) ? cnt[i] : 0;
  sh[t] = v; __syncthreads();
  for (int off = 1; off < 1024; off <<= 1){
    int x = (t >= off) ? sh[t-off] : 0;
    __syncthreads();
    sh[t] += x;
    __syncthreads();
  }
  if (i < NN) offs[i] = sh[t] - v;
  if (t == 1023) totals[blockIdx.x] = sh[t];
}

__global__ void k_scan_tops(int* totals, int nb){
  if (threadIdx.x == 0){
    int acc = 0;
    for (int i = 0; i < nb; i++){ int v = totals[i]; totals[i] = acc; acc += v; }
  }
}

__global__ void k_scan_add(int* __restrict__ offs, const int* __restrict__ totals, int* __restrict__ cursor){
  int i = blockIdx.x*blockDim.x + threadIdx.x;
  if (i < NN){
    int v = offs[i] + totals[i >> 10];
    offs[i] = v;
    cursor[i] = v;
  } else if (i == NN){
    offs[NN] = NE;
  }
}

__global__ void k_scatter(const int* __restrict__ ei, int* __restrict__ cursor,
                          int* __restrict__ ssrc, int* __restrict__ seid){
  int e = blockIdx.x*blockDim.x + threadIdx.x;
  if (e >= NE) return;
  int d = ei[NE + e];
  int p = atomicAdd(&cursor[d], 1);
  ssrc[p] = ei[e];
  seid[p] = e;
}

__global__ void k_sumlog(const int* __restrict__ cnt, float* __restrict__ sumlog){
  __shared__ float sh[256];
  int t = threadIdx.x;
  float s = 0.f;
  for (int i = blockIdx.x*256 + t; i < NN; i += gridDim.x*256)
    s += logf((float)cnt[i] + 1.f);
  sh[t] = s; __syncthreads();
  for (int o = 128; o > 0; o >>= 1){ if (t < o) sh[t] += sh[t+o]; __syncthreads(); }
  if (t == 0) atomicAdd(sumlog, sh[0]);
}

__global__ void k_rscale(const int* __restrict__ cnt, const float* __restrict__ sumlog,
                         float* __restrict__ r1, float* __restrict__ r2){
  int i = blockIdx.x*blockDim.x + threadIdx.x;
  if (i >= NN) return;
  float avg = sumlog[0] / (float)NN;
  float logd = logf(fmaxf((float)cnt[i], 1.f) + 1.f);
  r1[i] = logd / avg;
  r2[i] = avg / logd;
}

// ---------------- per-layer weight prep ----------------

__global__ void k_prep_edge(const float* __restrict__ we, const float* __restrict__ be,
                            const float* __restrict__ wp, const float* __restrict__ bp,
                            float* __restrict__ WeL, float* __restrict__ bL, int fi){
  int f = blockIdx.x*blockDim.x + threadIdx.x;
  if (f >= fi) return;
  const float* wpb = wp + (size_t)2*fi*fi;
  for (int r = 0; r < 13; r++){
    float s = 0.f;
    for (int j = 0; j < fi; j++) s += we[r*fi + j] * wpb[(size_t)j*fi + f];
    WeL[r*fi + f] = s;
  }
  float s = bp[f];
  for (int j = 0; j < fi; j++) s += be[j] * wpb[(size_t)j*fi + f];
  bL[f] = s;
}

// WolT[o][k] = bf16( (wo @ wl)[k][o] )
__global__ void k_prep_wolT(const float* __restrict__ wo, const float* __restrict__ wl,
                            short* __restrict__ WolT, int fo, int K13){
  int k = blockIdx.x;
  int o = threadIdx.x;
  float s = 0.f;
  for (int j = 0; j < fo; j++) s += wo[(size_t)k*fo + j] * wl[(size_t)j*fo + o];
  WolT[(size_t)o*K13 + k] = f2bf(s);
}

// wpT[s][f][j] = bf16( wp[(s*fi + j)][f] )
__global__ void k_prep_wpT(const float* __restrict__ wp, short* __restrict__ wpT, int fi){
  int idx = blockIdx.x*blockDim.x + threadIdx.x;
  if (idx >= 2*fi*fi) return;
  int s = idx/(fi*fi), rem = idx - s*fi*fi;
  int f = rem/fi, j = rem - f*fi;
  wpT[idx] = f2bf(wp[((size_t)s*fi + j)*fi + f]);
}

// wcT[c][k] = bf16(wc[k][c])
__global__ void k_prep_wcT(const float* __restrict__ wc, short* __restrict__ wcT){
  int idx = blockIdx.x*blockDim.x + threadIdx.x;
  if (idx >= 2560) return;
  int c = idx >> 8, k = idx & 255;
  wcT[idx] = f2bf(wc[k*10 + c]);
}

// ---------------- MFMA GEMM ----------------
// C[M,Nout] = A @ B (+bias). BT = bf16 [Nout][K]. A generated from fp32 sources:
// kb=k0/FI: 0 -> P0; else P1..P4 cyclic with scale {1,r1,r2} by (kb-1)>>2.
// Plain GEMM: FI = K.
__global__ __launch_bounds__(256) void k_mfma(int M, int Nout, int K, int FI,
    const float* __restrict__ P0, const float* __restrict__ P1,
    const float* __restrict__ P2, const float* __restrict__ P3,
    const float* __restrict__ P4,
    const float* __restrict__ r1, const float* __restrict__ r2,
    const short* __restrict__ BT, int ldbt,
    float* __restrict__ C, int ldc, const float* __restrict__ bias)
{
  __shared__ short As[64][32];   // [row][k] bf16, row stride 64B
  __shared__ short Bs[64][32];   // [col][k] bf16
  const float* Pt[5] = {P0, P1, P2, P3, P4};
  int tid = threadIdx.x;
  int lane = tid & 63, w = tid >> 6;
  int wr = w >> 1, wc = w & 1;
  int l15 = lane & 15, l16 = lane >> 4;
  int row0 = blockIdx.x*64, col0 = blockIdx.y*64;
  int sr = tid >> 2, sq = tid & 3;
  f32x4 acc[2][2] = {};
  for (int k0 = 0; k0 < K; k0 += 32){
    int kb = k0 / FI;
    int pi = (kb == 0) ? 0 : ((kb - 1) & 3) + 1;
    int sm = (kb == 0) ? 0 : ((kb - 1) >> 2);
    const float* __restrict__ P = Pt[pi];
    int j0 = k0 - kb*FI + sq*8;
    int gr = row0 + sr;
    bf16x8 av = {0,0,0,0,0,0,0,0};
    if (gr < M){
      const float4* src = (const float4*)(P + (size_t)gr*FI + j0);
      float4 f0 = src[0], f1 = src[1];
      float s = (sm == 1) ? r1[gr] : ((sm == 2) ? r2[gr] : 1.f);
      av[0]=f2bf(f0.x*s); av[1]=f2bf(f0.y*s); av[2]=f2bf(f0.z*s); av[3]=f2bf(f0.w*s);
      av[4]=f2bf(f1.x*s); av[5]=f2bf(f1.y*s); av[6]=f2bf(f1.z*s); av[7]=f2bf(f1.w*s);
    }
    *(bf16x8*)&As[sr][sq*8] = av;
    int gc = col0 + sr;
    bf16x8 bv = {0,0,0,0,0,0,0,0};
    if (gc < Nout)
      bv = *(const bf16x8*)(BT + (size_t)gc*ldbt + k0 + sq*8);
    *(bf16x8*)&Bs[sr][sq*8] = bv;
    __syncthreads();
    bf16x8 af[2], bg[2];
    #pragma unroll
    for (int m = 0; m < 2; m++) af[m] = *(bf16x8*)&As[wr*32 + m*16 + l15][l16*8];
    #pragma unroll
    for (int n = 0; n < 2; n++) bg[n] = *(bf16x8*)&Bs[wc*32 + n*16 + l15][l16*8];
    #pragma unroll
    for (int m = 0; m < 2; m++)
      #pragma unroll
      for (int n = 0; n < 2; n++)
        acc[m][n] = __builtin_amdgcn_mfma_f32_16x16x32_bf16(af[m], bg[n], acc[m][n], 0, 0, 0);
    __syncthreads();
  }
  #pragma unroll
  for (int m = 0; m < 2; m++){
    #pragma unroll
    for (int n = 0; n < 2; n++){
      int gcol = col0 + wc*32 + n*16 + l15;
      #pragma unroll
      for (int i = 0; i < 4; i++){
        int grow = row0 + wr*32 + m*16 + l16*4 + i;
        if (grow < M && gcol < Nout)
          C[(size_t)grow*ldc + gcol] = acc[m][n][i] + (bias ? bias[gcol] : 0.f);
      }
    }
  }
}

// ---------------- aggregation (CSR, per node) ----------------
__global__ void k_aggregate(const int* __restrict__ offs, const int* __restrict__ ssrc,
    const int* __restrict__ seid, const float* __restrict__ edge_attr,
    const float* __restrict__ t_d, const float* __restrict__ t_s,
    const float* __restrict__ WeL, const float* __restrict__ bL,
    float* __restrict__ mean, float* __restrict__ mn, float* __restrict__ mx,
    float* __restrict__ stdv, int fi){
  extern __shared__ float sh[];   // [13*fi] WeL then [fi] bL
  int tid = threadIdx.x;
  int npb = blockDim.x / fi;
  for (int i = tid; i < 14*fi; i += blockDim.x)
    sh[i] = (i < 13*fi) ? WeL[i] : bL[i - 13*fi];
  __syncthreads();
  int local = tid / fi, f = tid % fi;
  int n = blockIdx.x * npb + local;
  if (n >= NN) return;
  float base = t_d[(size_t)n*fi + f] + sh[13*fi + f];
  int e0 = offs[n], e1 = offs[n+1];
  float s = 0.f, s2 = 0.f, vmn = FLT_MAX, vmx = -FLT_MAX;
  for (int p = e0; p < e1; p++){
    int src = ssrc[p], eid = seid[p];
    const float* ea = edge_attr + (size_t)eid*13;
    float m = base + t_s[(size_t)src*fi + f];
    #pragma unroll
    for (int r = 0; r < 13; r++) m += ea[r] * sh[r*fi + f];
    s += m; s2 += m*m;
    vmn = fminf(vmn, m); vmx = fmaxf(vmx, m);
  }
  int c = e1 - e0;
  float denom = fmaxf((float)c, 1.f);
  float me = s/denom, me2 = s2/denom;
  float sd = sqrtf(fmaxf(me2 - me*me, 0.f) + 1e-5f);
  size_t o = (size_t)n*fi + f;
  mean[o] = me;
  stdv[o] = sd;
  mn[o] = (c > 0) ? vmn : 0.f;
  mx[o] = (c > 0) ? vmx : 0.f;
}

// ---------------- BatchNorm ----------------
__global__ void k_bn_reduce(const float* __restrict__ x, float* __restrict__ sums, int fo, int rows){
  __shared__ float sh[512];
  int tid = threadIdx.x;
  int col = tid % fo, grp = tid / fo, ngrp = 256 / fo;
  float s = 0.f, s2 = 0.f;
  int r0 = blockIdx.x * rows;
  int rend = min(r0 + rows, NN);
  for (int r = r0 + grp; r < rend; r += ngrp){
    float v = x[(size_t)r*fo + col];
    s += v; s2 += v*v;
  }
  sh[tid] = s; sh[256 + tid] = s2;
  __syncthreads();
  if (grp == 0){
    for (int g = 1; g < ngrp; g++){ s += sh[g*fo + col]; s2 += sh[256 + g*fo + col]; }
    atomicAdd(&sums[col], s);
    atomicAdd(&sums[fo + col], s2);
  }
}

__global__ void k_bn_apply(float* __restrict__ x, const float* __restrict__ sums,
                           const float* __restrict__ g, const float* __restrict__ b,
                           int fo, int total){
  int i = blockIdx.x*blockDim.x + threadIdx.x;
  if (i >= total) return;
  int col = i % fo;
  float mu = sums[col] / (float)NN;
  float var = sums[fo + col] / (float)NN - mu*mu;
  float v = (x[i] - mu) * rsqrtf(var + 1e-5f) * g[col] + b[col];
  x[i] = fmaxf(v, 0.f);
}

// ---------------- host ----------------
extern "C" void kernel_launch(void* const* d_in, const int* in_sizes, int n_in,
                              void* d_out, int out_size, void* d_ws, size_t ws_size,
                              hipStream_t stream){
  const float* x0 = (const float*)d_in[0];
  const int*   ei = (const int*)d_in[1];
  const float* ea = (const float*)d_in[2];
  const float* W[35];
  for (int i = 0; i < 35; i++) W[i] = (const float*)d_in[i];
  const float* wc = W[33];
  const float* bc = W[34];

  char* w = (char*)d_ws;
  auto alloc = [&](size_t bytes)->void*{
    void* p = (void*)w; w += (bytes + 255) & ~(size_t)255; return p;
  };
  int* cnt    = (int*)alloc((size_t)NN*4);
  int* offs   = (int*)alloc((size_t)(NN+1)*4);
  int* cursor = (int*)alloc((size_t)NN*4);
  int* totals = (int*)alloc(64*4);
  int* ssrc   = (int*)alloc((size_t)NE*4);
  int* seid   = (int*)alloc((size_t)NE*4);
  float* sumlog = (float*)alloc(256);
  float* r1   = (float*)alloc((size_t)NN*4);
  float* r2   = (float*)alloc((size_t)NN*4);
  float* bns  = (float*)alloc(512*4);
  float* WeL  = (float*)alloc(13*128*4);
  float* bL   = (float*)alloc(128*4);
  short* WolT = (short*)alloc((size_t)256*1664*2);
  short* wpT  = (short*)alloc((size_t)2*128*128*2);
  short* wcT  = (short*)alloc((size_t)10*256*2);
  float* agg[4];
  for (int a = 0; a < 4; a++) agg[a] = (float*)alloc((size_t)NN*128*4);
  float* bufA = (float*)alloc((size_t)NN*256*4);
  float* bufB = (float*)alloc((size_t)NN*256*4);

  hipMemsetAsync(cnt, 0, (size_t)NN*4, stream);
  hipMemsetAsync(sumlog, 0, 4, stream);
  k_count<<<(NE+255)/256, 256, 0, stream>>>(ei + NE, cnt);
  k_scan_part<<<49, 1024, 0, stream>>>(cnt, offs, totals);
  k_scan_tops<<<1, 64, 0, stream>>>(totals, 49);
  k_scan_add<<<(NN+256)/256, 256, 0, stream>>>(offs, totals, cursor);
  k_scatter<<<(NE+255)/256, 256, 0, stream>>>(ei, cursor, ssrc, seid);
  k_sumlog<<<256, 256, 0, stream>>>(cnt, sumlog);
  k_rscale<<<(NN+255)/256, 256, 0, stream>>>(cnt, sumlog, r1, r2);
  k_prep_wcT<<<10, 256, 0, stream>>>(wc, wcT);

  const float* xin = x0;
  float* xout = bufB;
  const int fis[3] = {32, 64, 128};
  const int GX = (NN + 63) / 64;
  for (int l = 0; l < 3; l++){
    int fi = fis[l], fo = 2*fi;
    const float* we = W[3+10*l+0], *be = W[3+10*l+1];
    const float* wp = W[3+10*l+2], *bp = W[3+10*l+3];
    const float* wo = W[3+10*l+4];
    const float* wl = W[3+10*l+6];
    const float* g  = W[3+10*l+8], *bb = W[3+10*l+9];

    float* t_d = xout;                       // [NN, fi] — dead before xout is rewritten
    float* t_s = xout + (size_t)NN*fi;       // [NN, fi]

    k_prep_edge<<<(fi+127)/128, 128, 0, stream>>>(we, be, wp, bp, WeL, bL, fi);
    k_prep_wolT<<<13*fi, fo, 0, stream>>>(wo, wl, WolT, fo, 13*fi);
    k_prep_wpT<<<(2*fi*fi+255)/256, 256, 0, stream>>>(wp, wpT, fi);

    dim3 gt(GX, (fi + 63) / 64);
    k_mfma<<<gt, 256, 0, stream>>>(NN, fi, fi, fi, xin, xin, xin, xin, xin,
        r1, r2, wpT, fi, t_d, fi, nullptr);
    k_mfma<<<gt, 256, 0, stream>>>(NN, fi, fi, fi, xin, xin, xin, xin, xin,
        r1, r2, wpT + (size_t)fi*fi, fi, t_s, fi, nullptr);

    int bs = (fi < 64) ? 64 : fi;
    int npb = bs / fi;
    k_aggregate<<<(NN+npb-1)/npb, bs, 14*fi*4, stream>>>(offs, ssrc, seid, ea, t_d, t_s,
        WeL, bL, agg[0], agg[1], agg[2], agg[3], fi);

    dim3 gz(GX, fo / 64);
    k_mfma<<<gz, 256, 0, stream>>>(NN, fo, 13*fi, fi, xin, agg[0], agg[1], agg[2], agg[3],
        r1, r2, WolT, 13*fi, xout, fo, nullptr);

    hipMemsetAsync(bns, 0, (size_t)2*fo*4, stream);
    k_bn_reduce<<<256, 256, 0, stream>>>(xout, bns, fo, (NN+255)/256);
    k_bn_apply<<<((NN*fo)+255)/256, 256, 0, stream>>>(xout, bns, g, bb, fo, NN*fo);

    xin = xout;
    xout = (xout == bufB) ? bufA : bufB;
  }

  dim3 gc(GX, 1);
  k_mfma<<<gc, 256, 0, stream>>>(NN, 10, 256, 256, xin, xin, xin, xin, xin,
      r1, r2, wcT, 256, (float*)d_out, 10, bc);
}

// Round 3
// 1449.663 us; speedup vs baseline: 2.3150x; 1.0519x over previous
//
#include <hip/hip_runtime.h>
#include <math.h>
#include <float.h>

#define NN 50000
#define NE 800000

typedef __attribute__((ext_vector_type(8))) short bf16x8;
typedef __attribute__((ext_vector_type(4))) float f32x4;

__device__ inline short f2bf(float f){
  union { float f; unsigned u; } v; v.f = f;
  unsigned u = v.u + 0x7FFFu + ((v.u >> 16) & 1u);
  return (short)(u >> 16);
}

__device__ inline float bf2f(short b){
  union { unsigned u; float f; } v;
  v.u = ((unsigned)(unsigned short)b) << 16;
  return v.f;
}

// ---------------- setup kernels ----------------

__global__ void k_count(const int* __restrict__ dst, int* __restrict__ cnt){
  int e = blockIdx.x*blockDim.x + threadIdx.x;
  if (e < NE) atomicAdd(&cnt[dst[e]], 1);
}

__global__ void k_scan_part(const int* __restrict__ cnt, int* __restrict__ offs, int* __restrict__ totals){
  __shared__ int sh[1024];
  int t = threadIdx.x, i = blockIdx.x*1024 + t;
  int v = (i < NN) ? cnt[i] : 0;
  sh[t] = v; __syncthreads();
  for (int off = 1; off < 1024; off <<= 1){
    int x = (t >= off) ? sh[t-off] : 0;
    __syncthreads();
    sh[t] += x;
    __syncthreads();
  }
  if (i < NN) offs[i] = sh[t] - v;
  if (t == 1023) totals[blockIdx.x] = sh[t];
}

__global__ void k_scan_tops(int* totals, int nb){
  if (threadIdx.x == 0){
    int acc = 0;
    for (int i = 0; i < nb; i++){ int v = totals[i]; totals[i] = acc; acc += v; }
  }
}

__global__ void k_scan_add(int* __restrict__ offs, const int* __restrict__ totals, int* __restrict__ cursor){
  int i = blockIdx.x*blockDim.x + threadIdx.x;
  if (i < NN){
    int v = offs[i] + totals[i >> 10];
    offs[i] = v;
    cursor[i] = v;
  } else if (i == NN){
    offs[NN] = NE;
  }
}

__global__ void k_scatter(const int* __restrict__ ei, int* __restrict__ cursor,
                          int* __restrict__ ssrc, int* __restrict__ seid){
  int e = blockIdx.x*blockDim.x + threadIdx.x;
  if (e >= NE) return;
  int d = ei[NE + e];
  int p = atomicAdd(&cursor[d], 1);
  ssrc[p] = ei[e];
  seid[p] = e;
}

// ea_s[p][0..15] = bf16(edge_attr[seid[p]][0..12]), padded with 0
__global__ void k_permute_ea(const float* __restrict__ ea, const int* __restrict__ seid,
                             short* __restrict__ ea_s){
  int i = blockIdx.x*blockDim.x + threadIdx.x;
  if (i >= NE*16) return;
  int p = i >> 4, r = i & 15;
  int eid = seid[p];
  float v = (r < 13) ? ea[(size_t)eid*13 + r] : 0.f;
  ea_s[i] = f2bf(v);
}

__global__ void k_sumlog(const int* __restrict__ cnt, float* __restrict__ sumlog){
  __shared__ float sh[256];
  int t = threadIdx.x;
  float s = 0.f;
  for (int i = blockIdx.x*256 + t; i < NN; i += gridDim.x*256)
    s += logf((float)cnt[i] + 1.f);
  sh[t] = s; __syncthreads();
  for (int o = 128; o > 0; o >>= 1){ if (t < o) sh[t] += sh[t+o]; __syncthreads(); }
  if (t == 0) atomicAdd(sumlog, sh[0]);
}

__global__ void k_rscale(const int* __restrict__ cnt, const float* __restrict__ sumlog,
                         float* __restrict__ r1, float* __restrict__ r2){
  int i = blockIdx.x*blockDim.x + threadIdx.x;
  if (i >= NN) return;
  float avg = sumlog[0] / (float)NN;
  float logd = logf(fmaxf((float)cnt[i], 1.f) + 1.f);
  r1[i] = logd / avg;
  r2[i] = avg / logd;
}

// ---------------- per-layer weight prep ----------------

__global__ void k_prep_edge(const float* __restrict__ we, const float* __restrict__ be,
                            const float* __restrict__ wp, const float* __restrict__ bp,
                            float* __restrict__ WeL, float* __restrict__ bL, int fi){
  int f = blockIdx.x*blockDim.x + threadIdx.x;
  if (f >= fi) return;
  const float* wpb = wp + (size_t)2*fi*fi;
  for (int r = 0; r < 13; r++){
    float s = 0.f;
    for (int j = 0; j < fi; j++) s += we[r*fi + j] * wpb[(size_t)j*fi + f];
    WeL[r*fi + f] = s;
  }
  float s = bp[f];
  for (int j = 0; j < fi; j++) s += be[j] * wpb[(size_t)j*fi + f];
  bL[f] = s;
}

// WolT[o][k] = bf16( (wo @ wl)[k][o] )
__global__ void k_prep_wolT(const float* __restrict__ wo, const float* __restrict__ wl,
                            short* __restrict__ WolT, int fo, int K13){
  int k = blockIdx.x;
  int o = threadIdx.x;
  float s = 0.f;
  for (int j = 0; j < fo; j++) s += wo[(size_t)k*fo + j] * wl[(size_t)j*fo + o];
  WolT[(size_t)o*K13 + k] = f2bf(s);
}

// wpT[s][f][j] = bf16( wp[(s*fi + j)][f] )
__global__ void k_prep_wpT(const float* __restrict__ wp, short* __restrict__ wpT, int fi){
  int idx = blockIdx.x*blockDim.x + threadIdx.x;
  if (idx >= 2*fi*fi) return;
  int s = idx/(fi*fi), rem = idx - s*fi*fi;
  int f = rem/fi, j = rem - f*fi;
  wpT[idx] = f2bf(wp[((size_t)s*fi + j)*fi + f]);
}

// wcT[c][k] = bf16(wc[k][c])
__global__ void k_prep_wcT(const float* __restrict__ wc, short* __restrict__ wcT){
  int idx = blockIdx.x*blockDim.x + threadIdx.x;
  if (idx >= 2560) return;
  int c = idx >> 8, k = idx & 255;
  wcT[idx] = f2bf(wc[k*10 + c]);
}

// ---------------- MFMA GEMM ----------------
// C[M,Nout] = A @ B (+bias). BT = bf16 [Nout][K]. A generated from fp32 sources:
// kb=k0/FI: 0 -> P0; else P1..P4 cyclic with scale {1,r1,r2} by (kb-1)>>2.
// Plain GEMM: FI = K.
__global__ __launch_bounds__(256) void k_mfma(int M, int Nout, int K, int FI,
    const float* __restrict__ P0, const float* __restrict__ P1,
    const float* __restrict__ P2, const float* __restrict__ P3,
    const float* __restrict__ P4,
    const float* __restrict__ r1, const float* __restrict__ r2,
    const short* __restrict__ BT, int ldbt,
    float* __restrict__ C, int ldc, const float* __restrict__ bias)
{
  __shared__ short As[64][32];   // [row][k] bf16, row stride 64B
  __shared__ short Bs[64][32];   // [col][k] bf16
  const float* Pt[5] = {P0, P1, P2, P3, P4};
  int tid = threadIdx.x;
  int lane = tid & 63, w = tid >> 6;
  int wr = w >> 1, wc = w & 1;
  int l15 = lane & 15, l16 = lane >> 4;
  int row0 = blockIdx.x*64, col0 = blockIdx.y*64;
  int sr = tid >> 2, sq = tid & 3;
  f32x4 acc[2][2] = {};
  for (int k0 = 0; k0 < K; k0 += 32){
    int kb = k0 / FI;
    int pi = (kb == 0) ? 0 : ((kb - 1) & 3) + 1;
    int sm = (kb == 0) ? 0 : ((kb - 1) >> 2);
    const float* __restrict__ P = Pt[pi];
    int j0 = k0 - kb*FI + sq*8;
    int gr = row0 + sr;
    bf16x8 av = {0,0,0,0,0,0,0,0};
    if (gr < M){
      const float4* src = (const float4*)(P + (size_t)gr*FI + j0);
      float4 f0 = src[0], f1 = src[1];
      float s = (sm == 1) ? r1[gr] : ((sm == 2) ? r2[gr] : 1.f);
      av[0]=f2bf(f0.x*s); av[1]=f2bf(f0.y*s); av[2]=f2bf(f0.z*s); av[3]=f2bf(f0.w*s);
      av[4]=f2bf(f1.x*s); av[5]=f2bf(f1.y*s); av[6]=f2bf(f1.z*s); av[7]=f2bf(f1.w*s);
    }
    *(bf16x8*)&As[sr][sq*8] = av;
    int gc = col0 + sr;
    bf16x8 bv = {0,0,0,0,0,0,0,0};
    if (gc < Nout)
      bv = *(const bf16x8*)(BT + (size_t)gc*ldbt + k0 + sq*8);
    *(bf16x8*)&Bs[sr][sq*8] = bv;
    __syncthreads();
    bf16x8 af[2], bg[2];
    #pragma unroll
    for (int m = 0; m < 2; m++) af[m] = *(bf16x8*)&As[wr*32 + m*16 + l15][l16*8];
    #pragma unroll
    for (int n = 0; n < 2; n++) bg[n] = *(bf16x8*)&Bs[wc*32 + n*16 + l15][l16*8];
    #pragma unroll
    for (int m = 0; m < 2; m++)
      #pragma unroll
      for (int n = 0; n < 2; n++)
        acc[m][n] = __builtin_amdgcn_mfma_f32_16x16x32_bf16(af[m], bg[n], acc[m][n], 0, 0, 0);
    __syncthreads();
  }
  #pragma unroll
  for (int m = 0; m < 2; m++){
    #pragma unroll
    for (int n = 0; n < 2; n++){
      int gcol = col0 + wc*32 + n*16 + l15;
      #pragma unroll
      for (int i = 0; i < 4; i++){
        int grow = row0 + wr*32 + m*16 + l16*4 + i;
        if (grow < M && gcol < Nout)
          C[(size_t)grow*ldc + gcol] = acc[m][n][i] + (bias ? bias[gcol] : 0.f);
      }
    }
  }
}

// ---------------- aggregation (CSR, per node; WeL in regs, bf16 permuted ea) ----
__global__ void k_aggregate(const int* __restrict__ offs, const int* __restrict__ ssrc,
    const short* __restrict__ ea_s,
    const float* __restrict__ t_d, const float* __restrict__ t_s,
    const float* __restrict__ WeL, const float* __restrict__ bL,
    float* __restrict__ mean, float* __restrict__ mn, float* __restrict__ mx,
    float* __restrict__ stdv, int fi){
  int tid = threadIdx.x;
  int npb = blockDim.x / fi;
  int local = tid / fi, f = tid % fi;
  int n = blockIdx.x * npb + local;
  if (n >= NN) return;
  float wreg[13];
  #pragma unroll
  for (int r = 0; r < 13; r++) wreg[r] = WeL[r*fi + f];
  float base = t_d[(size_t)n*fi + f] + bL[f];
  int e0 = offs[n], e1 = offs[n+1];
  float s = 0.f, s2 = 0.f, vmn = FLT_MAX, vmx = -FLT_MAX;
  for (int p = e0; p < e1; p++){
    int src = ssrc[p];
    const bf16x8* er = (const bf16x8*)(ea_s + (size_t)p*16);
    bf16x8 ev0 = er[0], ev1 = er[1];
    float m = base + t_s[(size_t)src*fi + f];
    #pragma unroll
    for (int r = 0; r < 8; r++) m += bf2f(ev0[r]) * wreg[r];
    #pragma unroll
    for (int r = 0; r < 5; r++) m += bf2f(ev1[r]) * wreg[8 + r];
    s += m; s2 += m*m;
    vmn = fminf(vmn, m); vmx = fmaxf(vmx, m);
  }
  int c = e1 - e0;
  float denom = fmaxf((float)c, 1.f);
  float me = s/denom, me2 = s2/denom;
  float sd = sqrtf(fmaxf(me2 - me*me, 0.f) + 1e-5f);
  size_t o = (size_t)n*fi + f;
  mean[o] = me;
  stdv[o] = sd;
  mn[o] = (c > 0) ? vmn : 0.f;
  mx[o] = (c > 0) ? vmx : 0.f;
}

// ---------------- BatchNorm ----------------
__global__ void k_bn_reduce(const float* __restrict__ x, float* __restrict__ sums, int fo, int rows){
  __shared__ float sh[512];
  int tid = threadIdx.x;
  int col = tid % fo, grp = tid / fo, ngrp = 256 / fo;
  float s = 0.f, s2 = 0.f;
  int r0 = blockIdx.x * rows;
  int rend = min(r0 + rows, NN);
  for (int r = r0 + grp; r < rend; r += ngrp){
    float v = x[(size_t)r*fo + col];
    s += v; s2 += v*v;
  }
  sh[tid] = s; sh[256 + tid] = s2;
  __syncthreads();
  if (grp == 0){
    for (int g = 1; g < ngrp; g++){ s += sh[g*fo + col]; s2 += sh[256 + g*fo + col]; }
    atomicAdd(&sums[col], s);
    atomicAdd(&sums[fo + col], s2);
  }
}

__global__ void k_bn_apply(float* __restrict__ x, const float* __restrict__ sums,
                           const float* __restrict__ g, const float* __restrict__ b,
                           int fo, int total){
  int i = blockIdx.x*blockDim.x + threadIdx.x;
  if (i >= total) return;
  int col = i % fo;
  float mu = sums[col] / (float)NN;
  float var = sums[fo + col] / (float)NN - mu*mu;
  float v = (x[i] - mu) * rsqrtf(var + 1e-5f) * g[col] + b[col];
  x[i] = fmaxf(v, 0.f);
}

// ---------------- host ----------------
extern "C" void kernel_launch(void* const* d_in, const int* in_sizes, int n_in,
                              void* d_out, int out_size, void* d_ws, size_t ws_size,
                              hipStream_t stream){
  const float* x0 = (const float*)d_in[0];
  const int*   ei = (const int*)d_in[1];
  const float* ea = (const float*)d_in[2];
  const float* W[35];
  for (int i = 0; i < 35; i++) W[i] = (const float*)d_in[i];
  const float* wc = W[33];
  const float* bc = W[34];

  char* w = (char*)d_ws;
  auto alloc = [&](size_t bytes)->void*{
    void* p = (void*)w; w += (bytes + 255) & ~(size_t)255; return p;
  };
  int* cnt    = (int*)alloc((size_t)NN*4);
  int* offs   = (int*)alloc((size_t)(NN+1)*4);
  int* cursor = (int*)alloc((size_t)NN*4);
  int* totals = (int*)alloc(64*4);
  int* ssrc   = (int*)alloc((size_t)NE*4);
  int* seid   = (int*)alloc((size_t)NE*4);
  float* sumlog = (float*)alloc(256);
  float* r1   = (float*)alloc((size_t)NN*4);
  float* r2   = (float*)alloc((size_t)NN*4);
  float* bns  = (float*)alloc(512*4);
  float* WeL  = (float*)alloc(13*128*4);
  float* bL   = (float*)alloc(128*4);
  short* WolT = (short*)alloc((size_t)256*1664*2);
  short* wpT  = (short*)alloc((size_t)2*128*128*2);
  short* wcT  = (short*)alloc((size_t)10*256*2);
  short* ea_s = (short*)alloc((size_t)NE*16*2);            // bf16, CSR-permuted, padded to 16
  float* agg[4];
  for (int a = 0; a < 4; a++) agg[a] = (float*)alloc((size_t)NN*128*4);
  float* bufA = (float*)alloc((size_t)NN*128*4);           // max use: L2 t_d/t_s + L2 out
  float* bufB = (float*)alloc((size_t)NN*256*4);           // max use: L3 t_d/t_s, L3 out

  hipMemsetAsync(cnt, 0, (size_t)NN*4, stream);
  hipMemsetAsync(sumlog, 0, 4, stream);
  k_count<<<(NE+255)/256, 256, 0, stream>>>(ei + NE, cnt);
  k_scan_part<<<49, 1024, 0, stream>>>(cnt, offs, totals);
  k_scan_tops<<<1, 64, 0, stream>>>(totals, 49);
  k_scan_add<<<(NN+256)/256, 256, 0, stream>>>(offs, totals, cursor);
  k_scatter<<<(NE+255)/256, 256, 0, stream>>>(ei, cursor, ssrc, seid);
  k_permute_ea<<<(NE*16+255)/256, 256, 0, stream>>>(ea, seid, ea_s);
  k_sumlog<<<256, 256, 0, stream>>>(cnt, sumlog);
  k_rscale<<<(NN+255)/256, 256, 0, stream>>>(cnt, sumlog, r1, r2);
  k_prep_wcT<<<10, 256, 0, stream>>>(wc, wcT);

  const float* xin = x0;
  float* xout = bufB;
  const int fis[3] = {32, 64, 128};
  const int GX = (NN + 63) / 64;
  for (int l = 0; l < 3; l++){
    int fi = fis[l], fo = 2*fi;
    const float* we = W[3+10*l+0], *be = W[3+10*l+1];
    const float* wp = W[3+10*l+2], *bp = W[3+10*l+3];
    const float* wo = W[3+10*l+4];
    const float* wl = W[3+10*l+6];
    const float* g  = W[3+10*l+8], *bb = W[3+10*l+9];

    float* t_d = xout;                       // [NN, fi] — dead before xout is rewritten
    float* t_s = xout + (size_t)NN*fi;       // [NN, fi]

    k_prep_edge<<<(fi+127)/128, 128, 0, stream>>>(we, be, wp, bp, WeL, bL, fi);
    k_prep_wolT<<<13*fi, fo, 0, stream>>>(wo, wl, WolT, fo, 13*fi);
    k_prep_wpT<<<(2*fi*fi+255)/256, 256, 0, stream>>>(wp, wpT, fi);

    dim3 gt(GX, (fi + 63) / 64);
    k_mfma<<<gt, 256, 0, stream>>>(NN, fi, fi, fi, xin, xin, xin, xin, xin,
        r1, r2, wpT, fi, t_d, fi, nullptr);
    k_mfma<<<gt, 256, 0, stream>>>(NN, fi, fi, fi, xin, xin, xin, xin, xin,
        r1, r2, wpT + (size_t)fi*fi, fi, t_s, fi, nullptr);

    int bs = (fi < 64) ? 64 : fi;
    int npb = bs / fi;
    k_aggregate<<<(NN+npb-1)/npb, bs, 0, stream>>>(offs, ssrc, ea_s, t_d, t_s,
        WeL, bL, agg[0], agg[1], agg[2], agg[3], fi);

    dim3 gz(GX, fo / 64);
    k_mfma<<<gz, 256, 0, stream>>>(NN, fo, 13*fi, fi, xin, agg[0], agg[1], agg[2], agg[3],
        r1, r2, WolT, 13*fi, xout, fo, nullptr);

    hipMemsetAsync(bns, 0, (size_t)2*fo*4, stream);
    k_bn_reduce<<<256, 256, 0, stream>>>(xout, bns, fo, (NN+255)/256);
    k_bn_apply<<<((NN*fo)+255)/256, 256, 0, stream>>>(xout, bns, g, bb, fo, NN*fo);

    xin = xout;
    xout = (xout == bufB) ? bufA : bufB;
  }

  dim3 gc(GX, 1);
  k_mfma<<<gc, 256, 0, stream>>>(NN, 10, 256, 256, xin, xin, xin, xin, xin,
      r1, r2, wcT, 256, (float*)d_out, 10, bc);
}

// Round 4
// 1169.788 us; speedup vs baseline: 2.8688x; 1.2393x over previous
//
#include <hip/hip_runtime.h>
#include <math.h>
#include <float.h>

#define NN 50000
#define NE 800000

typedef __attribute__((ext_vector_type(8))) short bf16x8;
typedef __attribute__((ext_vector_type(4))) float f32x4;

__device__ inline short f2bf(float f){
  union { float f; unsigned u; } v; v.f = f;
  unsigned u = v.u + 0x7FFFu + ((v.u >> 16) & 1u);
  return (short)(u >> 16);
}

__device__ inline float bf2f(short b){
  union { unsigned u; float f; } v;
  v.u = ((unsigned)(unsigned short)b) << 16;
  return v.f;
}

// ---------------- setup kernels ----------------

__global__ void k_count(const int* __restrict__ dst, int* __restrict__ cnt){
  int e = blockIdx.x*blockDim.x + threadIdx.x;
  if (e < NE) atomicAdd(&cnt[dst[e]], 1);
}

__global__ void k_scan_part(const int* __restrict__ cnt, int* __restrict__ offs, int* __restrict__ totals){
  __shared__ int sh[1024];
  int t = threadIdx.x, i = blockIdx.x*1024 + t;
  int v = (i < NN) ? cnt[i] : 0;
  sh[t] = v; __syncthreads();
  for (int off = 1; off < 1024; off <<= 1){
    int x = (t >= off) ? sh[t-off] : 0;
    __syncthreads();
    sh[t] += x;
    __syncthreads();
  }
  if (i < NN) offs[i] = sh[t] - v;
  if (t == 1023) totals[blockIdx.x] = sh[t];
}

__global__ void k_scan_tops(int* totals, int nb){
  if (threadIdx.x == 0){
    int acc = 0;
    for (int i = 0; i < nb; i++){ int v = totals[i]; totals[i] = acc; acc += v; }
  }
}

__global__ void k_scan_add(int* __restrict__ offs, const int* __restrict__ totals, int* __restrict__ cursor){
  int i = blockIdx.x*blockDim.x + threadIdx.x;
  if (i < NN){
    int v = offs[i] + totals[i >> 10];
    offs[i] = v;
    cursor[i] = v;
  } else if (i == NN){
    offs[NN] = NE;
  }
}

__global__ void k_scatter(const int* __restrict__ ei, int* __restrict__ cursor,
                          int* __restrict__ ssrc, int* __restrict__ seid){
  int e = blockIdx.x*blockDim.x + threadIdx.x;
  if (e >= NE) return;
  int d = ei[NE + e];
  int p = atomicAdd(&cursor[d], 1);
  ssrc[p] = ei[e];
  seid[p] = e;
}

// ea_s[p][0..15] = bf16(edge_attr[seid[p]][0..12]), padded with 0
__global__ void k_permute_ea(const float* __restrict__ ea, const int* __restrict__ seid,
                             short* __restrict__ ea_s){
  int i = blockIdx.x*blockDim.x + threadIdx.x;
  if (i >= NE*16) return;
  int p = i >> 4, r = i & 15;
  int eid = seid[p];
  float v = (r < 13) ? ea[(size_t)eid*13 + r] : 0.f;
  ea_s[i] = f2bf(v);
}

__global__ void k_sumlog(const int* __restrict__ cnt, float* __restrict__ sumlog){
  __shared__ float sh[256];
  int t = threadIdx.x;
  float s = 0.f;
  for (int i = blockIdx.x*256 + t; i < NN; i += gridDim.x*256)
    s += logf((float)cnt[i] + 1.f);
  sh[t] = s; __syncthreads();
  for (int o = 128; o > 0; o >>= 1){ if (t < o) sh[t] += sh[t+o]; __syncthreads(); }
  if (t == 0) atomicAdd(sumlog, sh[0]);
}

__global__ void k_rscale(const int* __restrict__ cnt, const float* __restrict__ sumlog,
                         float* __restrict__ r1, float* __restrict__ r2){
  int i = blockIdx.x*blockDim.x + threadIdx.x;
  if (i >= NN) return;
  float avg = sumlog[0] / (float)NN;
  float logd = logf(fmaxf((float)cnt[i], 1.f) + 1.f);
  r1[i] = logd / avg;
  r2[i] = avg / logd;
}

// ---------------- per-layer weight prep ----------------

// one thread per output element: idx = r*fi + f, r<13 -> WeL row, r==13 -> bL
__global__ void k_prep_edge(const float* __restrict__ we, const float* __restrict__ be,
                            const float* __restrict__ wp, const float* __restrict__ bp,
                            float* __restrict__ WeL, float* __restrict__ bL, int fi){
  int idx = blockIdx.x*blockDim.x + threadIdx.x;
  if (idx >= 14*fi) return;
  int r = idx / fi, f = idx - r*fi;
  const float* wpb = wp + (size_t)2*fi*fi;
  if (r < 13){
    const float* wr = we + r*fi;
    float s = 0.f;
    for (int j = 0; j < fi; j++) s += wr[j] * wpb[(size_t)j*fi + f];
    WeL[r*fi + f] = s;
  } else {
    float s = bp[f];
    for (int j = 0; j < fi; j++) s += be[j] * wpb[(size_t)j*fi + f];
    bL[f] = s;
  }
}

// WolT[o][k] = bf16( (wo @ wl)[k][o] )
__global__ void k_prep_wolT(const float* __restrict__ wo, const float* __restrict__ wl,
                            short* __restrict__ WolT, int fo, int K13){
  int k = blockIdx.x;
  int o = threadIdx.x;
  float s = 0.f;
  for (int j = 0; j < fo; j++) s += wo[(size_t)k*fo + j] * wl[(size_t)j*fo + o];
  WolT[(size_t)o*K13 + k] = f2bf(s);
}

// wpT[s][f][j] = bf16( wp[(s*fi + j)][f] )
__global__ void k_prep_wpT(const float* __restrict__ wp, short* __restrict__ wpT, int fi){
  int idx = blockIdx.x*blockDim.x + threadIdx.x;
  if (idx >= 2*fi*fi) return;
  int s = idx/(fi*fi), rem = idx - s*fi*fi;
  int f = rem/fi, j = rem - f*fi;
  wpT[idx] = f2bf(wp[((size_t)s*fi + j)*fi + f]);
}

// wcT[c][k] = bf16(wc[k][c])
__global__ void k_prep_wcT(const float* __restrict__ wc, short* __restrict__ wcT){
  int idx = blockIdx.x*blockDim.x + threadIdx.x;
  if (idx >= 2560) return;
  int c = idx >> 8, k = idx & 255;
  wcT[idx] = f2bf(wc[k*10 + c]);
}

// ---------------- MFMA GEMM ----------------
// C[M,Nout] = A @ B (+bias). BT = bf16 [Nout][K]. A generated from fp32 sources:
// kb=k0/FI: 0 -> P0; else P1..P4 cyclic with scale {1,r1,r2} by (kb-1)>>2.
// Plain GEMM: FI = K.
__global__ __launch_bounds__(256) void k_mfma(int M, int Nout, int K, int FI,
    const float* __restrict__ P0, const float* __restrict__ P1,
    const float* __restrict__ P2, const float* __restrict__ P3,
    const float* __restrict__ P4,
    const float* __restrict__ r1, const float* __restrict__ r2,
    const short* __restrict__ BT, int ldbt,
    float* __restrict__ C, int ldc, const float* __restrict__ bias)
{
  __shared__ short As[64][32];   // [row][k] bf16, row stride 64B
  __shared__ short Bs[64][32];   // [col][k] bf16
  const float* Pt[5] = {P0, P1, P2, P3, P4};
  int tid = threadIdx.x;
  int lane = tid & 63, w = tid >> 6;
  int wr = w >> 1, wc = w & 1;
  int l15 = lane & 15, l16 = lane >> 4;
  int row0 = blockIdx.x*64, col0 = blockIdx.y*64;
  int sr = tid >> 2, sq = tid & 3;
  f32x4 acc[2][2] = {};
  for (int k0 = 0; k0 < K; k0 += 32){
    int kb = k0 / FI;
    int pi = (kb == 0) ? 0 : ((kb - 1) & 3) + 1;
    int sm = (kb == 0) ? 0 : ((kb - 1) >> 2);
    const float* __restrict__ P = Pt[pi];
    int j0 = k0 - kb*FI + sq*8;
    int gr = row0 + sr;
    bf16x8 av = {0,0,0,0,0,0,0,0};
    if (gr < M){
      const float4* src = (const float4*)(P + (size_t)gr*FI + j0);
      float4 f0 = src[0], f1 = src[1];
      float s = (sm == 1) ? r1[gr] : ((sm == 2) ? r2[gr] : 1.f);
      av[0]=f2bf(f0.x*s); av[1]=f2bf(f0.y*s); av[2]=f2bf(f0.z*s); av[3]=f2bf(f0.w*s);
      av[4]=f2bf(f1.x*s); av[5]=f2bf(f1.y*s); av[6]=f2bf(f1.z*s); av[7]=f2bf(f1.w*s);
    }
    *(bf16x8*)&As[sr][sq*8] = av;
    int gc = col0 + sr;
    bf16x8 bv = {0,0,0,0,0,0,0,0};
    if (gc < Nout)
      bv = *(const bf16x8*)(BT + (size_t)gc*ldbt + k0 + sq*8);
    *(bf16x8*)&Bs[sr][sq*8] = bv;
    __syncthreads();
    bf16x8 af[2], bg[2];
    #pragma unroll
    for (int m = 0; m < 2; m++) af[m] = *(bf16x8*)&As[wr*32 + m*16 + l15][l16*8];
    #pragma unroll
    for (int n = 0; n < 2; n++) bg[n] = *(bf16x8*)&Bs[wc*32 + n*16 + l15][l16*8];
    #pragma unroll
    for (int m = 0; m < 2; m++)
      #pragma unroll
      for (int n = 0; n < 2; n++)
        acc[m][n] = __builtin_amdgcn_mfma_f32_16x16x32_bf16(af[m], bg[n], acc[m][n], 0, 0, 0);
    __syncthreads();
  }
  #pragma unroll
  for (int m = 0; m < 2; m++){
    #pragma unroll
    for (int n = 0; n < 2; n++){
      int gcol = col0 + wc*32 + n*16 + l15;
      #pragma unroll
      for (int i = 0; i < 4; i++){
        int grow = row0 + wr*32 + m*16 + l16*4 + i;
        if (grow < M && gcol < Nout)
          C[(size_t)grow*ldc + gcol] = acc[m][n][i] + (bias ? bias[gcol] : 0.f);
      }
    }
  }
}

// ---------------- aggregation (CSR, per node; WeL in regs, bf16 permuted ea) ----
__global__ void k_aggregate(const int* __restrict__ offs, const int* __restrict__ ssrc,
    const short* __restrict__ ea_s,
    const float* __restrict__ t_d, const float* __restrict__ t_s,
    const float* __restrict__ WeL, const float* __restrict__ bL,
    float* __restrict__ mean, float* __restrict__ mn, float* __restrict__ mx,
    float* __restrict__ stdv, int fi){
  int tid = threadIdx.x;
  int npb = blockDim.x / fi;
  int local = tid / fi, f = tid % fi;
  int n = blockIdx.x * npb + local;
  if (n >= NN) return;
  float wreg[13];
  #pragma unroll
  for (int r = 0; r < 13; r++) wreg[r] = WeL[r*fi + f];
  float base = t_d[(size_t)n*fi + f] + bL[f];
  int e0 = offs[n], e1 = offs[n+1];
  float s = 0.f, s2 = 0.f, vmn = FLT_MAX, vmx = -FLT_MAX;
  for (int p = e0; p < e1; p++){
    int src = ssrc[p];
    const bf16x8* er = (const bf16x8*)(ea_s + (size_t)p*16);
    bf16x8 ev0 = er[0], ev1 = er[1];
    float m = base + t_s[(size_t)src*fi + f];
    #pragma unroll
    for (int r = 0; r < 8; r++) m += bf2f(ev0[r]) * wreg[r];
    #pragma unroll
    for (int r = 0; r < 5; r++) m += bf2f(ev1[r]) * wreg[8 + r];
    s += m; s2 += m*m;
    vmn = fminf(vmn, m); vmx = fmaxf(vmx, m);
  }
  int c = e1 - e0;
  float denom = fmaxf((float)c, 1.f);
  float me = s/denom, me2 = s2/denom;
  float sd = sqrtf(fmaxf(me2 - me*me, 0.f) + 1e-5f);
  size_t o = (size_t)n*fi + f;
  mean[o] = me;
  stdv[o] = sd;
  mn[o] = (c > 0) ? vmn : 0.f;
  mx[o] = (c > 0) ? vmx : 0.f;
}

// ---------------- BatchNorm ----------------
__global__ void k_bn_reduce(const float* __restrict__ x, float* __restrict__ sums, int fo, int rows){
  __shared__ float sh[512];
  int tid = threadIdx.x;
  int col = tid % fo, grp = tid / fo, ngrp = 256 / fo;
  float s = 0.f, s2 = 0.f;
  int r0 = blockIdx.x * rows;
  int rend = min(r0 + rows, NN);
  for (int r = r0 + grp; r < rend; r += ngrp){
    float v = x[(size_t)r*fo + col];
    s += v; s2 += v*v;
  }
  sh[tid] = s; sh[256 + tid] = s2;
  __syncthreads();
  if (grp == 0){
    for (int g = 1; g < ngrp; g++){ s += sh[g*fo + col]; s2 += sh[256 + g*fo + col]; }
    atomicAdd(&sums[col], s);
    atomicAdd(&sums[fo + col], s2);
  }
}

__global__ void k_bn_apply(float* __restrict__ x, const float* __restrict__ sums,
                           const float* __restrict__ g, const float* __restrict__ b,
                           int fo, int total){
  int i = blockIdx.x*blockDim.x + threadIdx.x;
  if (i >= total) return;
  int col = i % fo;
  float mu = sums[col] / (float)NN;
  float var = sums[fo + col] / (float)NN - mu*mu;
  float v = (x[i] - mu) * rsqrtf(var + 1e-5f) * g[col] + b[col];
  x[i] = fmaxf(v, 0.f);
}

// ---------------- host ----------------
extern "C" void kernel_launch(void* const* d_in, const int* in_sizes, int n_in,
                              void* d_out, int out_size, void* d_ws, size_t ws_size,
                              hipStream_t stream){
  const float* x0 = (const float*)d_in[0];
  const int*   ei = (const int*)d_in[1];
  const float* ea = (const float*)d_in[2];
  const float* W[35];
  for (int i = 0; i < 35; i++) W[i] = (const float*)d_in[i];
  const float* wc = W[33];
  const float* bc = W[34];

  char* w = (char*)d_ws;
  auto alloc = [&](size_t bytes)->void*{
    void* p = (void*)w; w += (bytes + 255) & ~(size_t)255; return p;
  };
  int* cnt    = (int*)alloc((size_t)NN*4);
  int* offs   = (int*)alloc((size_t)(NN+1)*4);
  int* cursor = (int*)alloc((size_t)NN*4);
  int* totals = (int*)alloc(64*4);
  int* ssrc   = (int*)alloc((size_t)NE*4);
  int* seid   = (int*)alloc((size_t)NE*4);
  float* sumlog = (float*)alloc(256);
  float* r1   = (float*)alloc((size_t)NN*4);
  float* r2   = (float*)alloc((size_t)NN*4);
  float* bns  = (float*)alloc(512*4);
  float* WeL  = (float*)alloc(13*128*4);
  float* bL   = (float*)alloc(128*4);
  short* WolT = (short*)alloc((size_t)256*1664*2);
  short* wpT  = (short*)alloc((size_t)2*128*128*2);
  short* wcT  = (short*)alloc((size_t)10*256*2);
  short* ea_s = (short*)alloc((size_t)NE*16*2);            // bf16, CSR-permuted, padded to 16
  float* agg[4];
  for (int a = 0; a < 4; a++) agg[a] = (float*)alloc((size_t)NN*128*4);
  float* bufA = (float*)alloc((size_t)NN*128*4);           // max use: L2 t_d/t_s + L2 out
  float* bufB = (float*)alloc((size_t)NN*256*4);           // max use: L3 t_d/t_s, L3 out

  hipMemsetAsync(cnt, 0, (size_t)NN*4, stream);
  hipMemsetAsync(sumlog, 0, 4, stream);
  k_count<<<(NE+255)/256, 256, 0, stream>>>(ei + NE, cnt);
  k_scan_part<<<49, 1024, 0, stream>>>(cnt, offs, totals);
  k_scan_tops<<<1, 64, 0, stream>>>(totals, 49);
  k_scan_add<<<(NN+256)/256, 256, 0, stream>>>(offs, totals, cursor);
  k_scatter<<<(NE+255)/256, 256, 0, stream>>>(ei, cursor, ssrc, seid);
  k_permute_ea<<<(NE*16+255)/256, 256, 0, stream>>>(ea, seid, ea_s);
  k_sumlog<<<256, 256, 0, stream>>>(cnt, sumlog);
  k_rscale<<<(NN+255)/256, 256, 0, stream>>>(cnt, sumlog, r1, r2);
  k_prep_wcT<<<10, 256, 0, stream>>>(wc, wcT);

  const float* xin = x0;
  float* xout = bufB;
  const int fis[3] = {32, 64, 128};
  const int GX = (NN + 63) / 64;
  for (int l = 0; l < 3; l++){
    int fi = fis[l], fo = 2*fi;
    const float* we = W[3+10*l+0], *be = W[3+10*l+1];
    const float* wp = W[3+10*l+2], *bp = W[3+10*l+3];
    const float* wo = W[3+10*l+4];
    const float* wl = W[3+10*l+6];
    const float* g  = W[3+10*l+8], *bb = W[3+10*l+9];

    float* t_d = xout;                       // [NN, fi] — dead before xout is rewritten
    float* t_s = xout + (size_t)NN*fi;       // [NN, fi]

    k_prep_edge<<<(14*fi+255)/256, 256, 0, stream>>>(we, be, wp, bp, WeL, bL, fi);
    k_prep_wolT<<<13*fi, fo, 0, stream>>>(wo, wl, WolT, fo, 13*fi);
    k_prep_wpT<<<(2*fi*fi+255)/256, 256, 0, stream>>>(wp, wpT, fi);

    dim3 gt(GX, (fi + 63) / 64);
    k_mfma<<<gt, 256, 0, stream>>>(NN, fi, fi, fi, xin, xin, xin, xin, xin,
        r1, r2, wpT, fi, t_d, fi, nullptr);
    k_mfma<<<gt, 256, 0, stream>>>(NN, fi, fi, fi, xin, xin, xin, xin, xin,
        r1, r2, wpT + (size_t)fi*fi, fi, t_s, fi, nullptr);

    int bs = (fi < 64) ? 64 : fi;
    int npb = bs / fi;
    k_aggregate<<<(NN+npb-1)/npb, bs, 0, stream>>>(offs, ssrc, ea_s, t_d, t_s,
        WeL, bL, agg[0], agg[1], agg[2], agg[3], fi);

    dim3 gz(GX, fo / 64);
    k_mfma<<<gz, 256, 0, stream>>>(NN, fo, 13*fi, fi, xin, agg[0], agg[1], agg[2], agg[3],
        r1, r2, WolT, 13*fi, xout, fo, nullptr);

    hipMemsetAsync(bns, 0, (size_t)2*fo*4, stream);
    k_bn_reduce<<<256, 256, 0, stream>>>(xout, bns, fo, (NN+255)/256);
    k_bn_apply<<<((NN*fo)+255)/256, 256, 0, stream>>>(xout, bns, g, bb, fo, NN*fo);

    xin = xout;
    xout = (xout == bufB) ? bufA : bufB;
  }

  dim3 gc(GX, 1);
  k_mfma<<<gc, 256, 0, stream>>>(NN, 10, 256, 256, xin, xin, xin, xin, xin,
      r1, r2, wcT, 256, (float*)d_out, 10, bc);
}

// Round 5
// 1004.595 us; speedup vs baseline: 3.3406x; 1.1644x over previous
//
#include <hip/hip_runtime.h>
#include <math.h>
#include <float.h>

#define NN 50000
#define NE 800000

typedef __attribute__((ext_vector_type(8))) short bf16x8;
typedef __attribute__((ext_vector_type(4))) float f32x4;

__device__ inline short f2bf(float f){
  union { float f; unsigned u; } v; v.f = f;
  unsigned u = v.u + 0x7FFFu + ((v.u >> 16) & 1u);
  return (short)(u >> 16);
}

__device__ inline float bf2f(short b){
  union { unsigned u; float f; } v;
  v.u = ((unsigned)(unsigned short)b) << 16;
  return v.f;
}

// ---------------- setup kernels ----------------

__global__ void k_count(const int* __restrict__ dst, int* __restrict__ cnt){
  int e = blockIdx.x*blockDim.x + threadIdx.x;
  if (e < NE) atomicAdd(&cnt[dst[e]], 1);
}

__global__ void k_scan_part(const int* __restrict__ cnt, int* __restrict__ offs, int* __restrict__ totals){
  __shared__ int sh[1024];
  int t = threadIdx.x, i = blockIdx.x*1024 + t;
  int v = (i < NN) ? cnt[i] : 0;
  sh[t] = v; __syncthreads();
  for (int off = 1; off < 1024; off <<= 1){
    int x = (t >= off) ? sh[t-off] : 0;
    __syncthreads();
    sh[t] += x;
    __syncthreads();
  }
  if (i < NN) offs[i] = sh[t] - v;
  if (t == 1023) totals[blockIdx.x] = sh[t];
}

__global__ void k_scan_tops(int* totals, int nb){
  if (threadIdx.x == 0){
    int acc = 0;
    for (int i = 0; i < nb; i++){ int v = totals[i]; totals[i] = acc; acc += v; }
  }
}

__global__ void k_scan_add(int* __restrict__ offs, const int* __restrict__ totals, int* __restrict__ cursor){
  int i = blockIdx.x*blockDim.x + threadIdx.x;
  if (i < NN){
    int v = offs[i] + totals[i >> 10];
    offs[i] = v;
    cursor[i] = v;
  } else if (i == NN){
    offs[NN] = NE;
  }
}

__global__ void k_scatter(const int* __restrict__ ei, int* __restrict__ cursor,
                          int* __restrict__ ssrc, int* __restrict__ seid){
  int e = blockIdx.x*blockDim.x + threadIdx.x;
  if (e >= NE) return;
  int d = ei[NE + e];
  int p = atomicAdd(&cursor[d], 1);
  ssrc[p] = ei[e];
  seid[p] = e;
}

// ea_s[p][0..15] = bf16(edge_attr[seid[p]][0..12]), padded with 0
__global__ void k_permute_ea(const float* __restrict__ ea, const int* __restrict__ seid,
                             short* __restrict__ ea_s){
  int i = blockIdx.x*blockDim.x + threadIdx.x;
  if (i >= NE*16) return;
  int p = i >> 4, r = i & 15;
  int eid = seid[p];
  float v = (r < 13) ? ea[(size_t)eid*13 + r] : 0.f;
  ea_s[i] = f2bf(v);
}

__global__ void k_sumlog(const int* __restrict__ cnt, float* __restrict__ sumlog){
  __shared__ float sh[256];
  int t = threadIdx.x;
  float s = 0.f;
  for (int i = blockIdx.x*256 + t; i < NN; i += gridDim.x*256)
    s += logf((float)cnt[i] + 1.f);
  sh[t] = s; __syncthreads();
  for (int o = 128; o > 0; o >>= 1){ if (t < o) sh[t] += sh[t+o]; __syncthreads(); }
  if (t == 0) atomicAdd(sumlog, sh[0]);
}

__global__ void k_rscale(const int* __restrict__ cnt, const float* __restrict__ sumlog,
                         float* __restrict__ r1, float* __restrict__ r2){
  int i = blockIdx.x*blockDim.x + threadIdx.x;
  if (i >= NN) return;
  float avg = sumlog[0] / (float)NN;
  float logd = logf(fmaxf((float)cnt[i], 1.f) + 1.f);
  r1[i] = logd / avg;
  r2[i] = avg / logd;
}

// fp32 -> bf16 array convert
__global__ void k_f2bf_arr(const float* __restrict__ in, short* __restrict__ out, int n){
  int i = blockIdx.x*blockDim.x + threadIdx.x;
  if (i < n) out[i] = f2bf(in[i]);
}

// ---------------- per-layer weight prep ----------------

// one thread per output element: idx = r*fi + f, r<13 -> WeL row, r==13 -> bL
__global__ void k_prep_edge(const float* __restrict__ we, const float* __restrict__ be,
                            const float* __restrict__ wp, const float* __restrict__ bp,
                            float* __restrict__ WeL, float* __restrict__ bL, int fi){
  int idx = blockIdx.x*blockDim.x + threadIdx.x;
  if (idx >= 14*fi) return;
  int r = idx / fi, f = idx - r*fi;
  const float* wpb = wp + (size_t)2*fi*fi;
  if (r < 13){
    const float* wr = we + r*fi;
    float s = 0.f;
    for (int j = 0; j < fi; j++) s += wr[j] * wpb[(size_t)j*fi + f];
    WeL[r*fi + f] = s;
  } else {
    float s = bp[f];
    for (int j = 0; j < fi; j++) s += be[j] * wpb[(size_t)j*fi + f];
    bL[f] = s;
  }
}

// WolT[o][k] = bf16( (wo @ wl)[k][o] )
__global__ void k_prep_wolT(const float* __restrict__ wo, const float* __restrict__ wl,
                            short* __restrict__ WolT, int fo, int K13){
  int k = blockIdx.x;
  int o = threadIdx.x;
  float s = 0.f;
  for (int j = 0; j < fo; j++) s += wo[(size_t)k*fo + j] * wl[(size_t)j*fo + o];
  WolT[(size_t)o*K13 + k] = f2bf(s);
}

// wpT[s][f][j] = bf16( wp[(s*fi + j)][f] )
__global__ void k_prep_wpT(const float* __restrict__ wp, short* __restrict__ wpT, int fi){
  int idx = blockIdx.x*blockDim.x + threadIdx.x;
  if (idx >= 2*fi*fi) return;
  int s = idx/(fi*fi), rem = idx - s*fi*fi;
  int f = rem/fi, j = rem - f*fi;
  wpT[idx] = f2bf(wp[((size_t)s*fi + j)*fi + f]);
}

// wcT[c][k] = bf16(wc[k][c])
__global__ void k_prep_wcT(const float* __restrict__ wc, short* __restrict__ wcT){
  int idx = blockIdx.x*blockDim.x + threadIdx.x;
  if (idx >= 2560) return;
  int c = idx >> 8, k = idx & 255;
  wcT[idx] = f2bf(wc[k*10 + c]);
}

// ---------------- MFMA GEMM (64x64 tile, bf16 A sources) ----------------
// C[M,Nout] = A @ B (+bias). BT bf16 [Nout][K]. A from bf16 sources:
// kb=k0/FI: 0 -> P0; else P1..P4 cyclic, scale {1,r1,r2} by (kb-1)>>2. Plain: FI=K.
__global__ __launch_bounds__(256) void k_mfma(int M, int Nout, int K, int FI,
    const short* __restrict__ P0, const short* __restrict__ P1,
    const short* __restrict__ P2, const short* __restrict__ P3,
    const short* __restrict__ P4,
    const float* __restrict__ r1, const float* __restrict__ r2,
    const short* __restrict__ BT, int ldbt,
    float* __restrict__ C, int ldc, const float* __restrict__ bias)
{
  __shared__ short As[64*40];   // row stride 40 shorts (80B) — conflict-free-ish
  __shared__ short Bs[64*40];
  const short* Pt[5] = {P0, P1, P2, P3, P4};
  int tid = threadIdx.x;
  int lane = tid & 63, w = tid >> 6;
  int wr = w >> 1, wc = w & 1;
  int l15 = lane & 15, l16 = lane >> 4;
  int row0 = blockIdx.x*64, col0 = blockIdx.y*64;
  int sr = tid >> 2, sq = tid & 3;
  f32x4 acc[2][2] = {};
  for (int k0 = 0; k0 < K; k0 += 32){
    int kb = k0 / FI;
    int pi = (kb == 0) ? 0 : ((kb - 1) & 3) + 1;
    int sm = (kb == 0) ? 0 : ((kb - 1) >> 2);
    const short* __restrict__ P = Pt[pi];
    int j0 = k0 - kb*FI + sq*8;
    int gr = row0 + sr;
    bf16x8 av = {0,0,0,0,0,0,0,0};
    if (gr < M){
      av = *(const bf16x8*)(P + (size_t)gr*FI + j0);
      if (sm){
        float s = (sm == 1) ? r1[gr] : r2[gr];
        #pragma unroll
        for (int e = 0; e < 8; e++) av[e] = f2bf(bf2f(av[e]) * s);
      }
    }
    *(bf16x8*)&As[sr*40 + sq*8] = av;
    int gc = col0 + sr;
    bf16x8 bv = {0,0,0,0,0,0,0,0};
    if (gc < Nout)
      bv = *(const bf16x8*)(BT + (size_t)gc*ldbt + k0 + sq*8);
    *(bf16x8*)&Bs[sr*40 + sq*8] = bv;
    __syncthreads();
    bf16x8 af[2], bg[2];
    #pragma unroll
    for (int m = 0; m < 2; m++) af[m] = *(bf16x8*)&As[(wr*32 + m*16 + l15)*40 + l16*8];
    #pragma unroll
    for (int n = 0; n < 2; n++) bg[n] = *(bf16x8*)&Bs[(wc*32 + n*16 + l15)*40 + l16*8];
    #pragma unroll
    for (int m = 0; m < 2; m++)
      #pragma unroll
      for (int n = 0; n < 2; n++)
        acc[m][n] = __builtin_amdgcn_mfma_f32_16x16x32_bf16(af[m], bg[n], acc[m][n], 0, 0, 0);
    __syncthreads();
  }
  #pragma unroll
  for (int m = 0; m < 2; m++){
    #pragma unroll
    for (int n = 0; n < 2; n++){
      int gcol = col0 + wc*32 + n*16 + l15;
      #pragma unroll
      for (int i = 0; i < 4; i++){
        int grow = row0 + wr*32 + m*16 + l16*4 + i;
        if (grow < M && gcol < Nout)
          C[(size_t)grow*ldc + gcol] = acc[m][n][i] + (bias ? bias[gcol] : 0.f);
      }
    }
  }
}

// ---------------- big-tile MFMA GEMM: 256 rows x full-N, 512 threads -------
// Nout = MREP*32 covered entirely by one block (WCG = MREP/2 wave-col groups).
template<int MREP>
__global__ __launch_bounds__(512) void k_mfma_big(int M, int K, int FI,
    const short* __restrict__ P0, const short* __restrict__ P1,
    const short* __restrict__ P2, const short* __restrict__ P3,
    const short* __restrict__ P4,
    const float* __restrict__ r1, const float* __restrict__ r2,
    const short* __restrict__ BT,
    float* __restrict__ C)
{
  constexpr int WCG = MREP/2;          // wave col groups (Nout/64)
  constexpr int NOUT = WCG*64;
  __shared__ short As[256*40];
  __shared__ short Bs[256*40];         // only NOUT*40 used
  const short* Pt[5] = {P0, P1, P2, P3, P4};
  int tid = threadIdx.x;
  int lane = tid & 63, w = tid >> 6;
  int wid_c = w % WCG, wid_r = w / WCG;
  int wrow = wid_r * (MREP*16);
  int wcol = wid_c * 64;
  int l15 = lane & 15, l16 = lane >> 4;
  int row0 = blockIdx.x*256;
  int trow = tid >> 1, tseg = tid & 1;
  f32x4 acc[MREP][4] = {};
  for (int k0 = 0; k0 < K; k0 += 32){
    int kb = k0 / FI;
    int pi = (kb == 0) ? 0 : ((kb - 1) & 3) + 1;
    int sm = (kb == 0) ? 0 : ((kb - 1) >> 2);
    const short* __restrict__ P = Pt[pi];
    int j0 = k0 - kb*FI + tseg*16;
    // A stage: 256 rows x 32k, 2 threads/row
    int gr = row0 + trow;
    bf16x8 a0 = {0,0,0,0,0,0,0,0}, a1 = a0;
    if (gr < M){
      const short* src = P + (size_t)gr*FI + j0;
      a0 = *(const bf16x8*)src;
      a1 = *(const bf16x8*)(src + 8);
      if (sm){
        float s = (sm == 1) ? r1[gr] : r2[gr];
        #pragma unroll
        for (int e = 0; e < 8; e++){ a0[e] = f2bf(bf2f(a0[e])*s); a1[e] = f2bf(bf2f(a1[e])*s); }
      }
    }
    *(bf16x8*)&As[trow*40 + tseg*16] = a0;
    *(bf16x8*)&As[trow*40 + tseg*16 + 8] = a1;
    // B stage: NOUT cols x 32k
    if (trow < NOUT){
      const short* src = BT + (size_t)trow*K + k0 + tseg*16;
      *(bf16x8*)&Bs[trow*40 + tseg*16]     = *(const bf16x8*)src;
      *(bf16x8*)&Bs[trow*40 + tseg*16 + 8] = *(const bf16x8*)(src + 8);
    }
    __syncthreads();
    bf16x8 af[MREP], bg[4];
    #pragma unroll
    for (int m = 0; m < MREP; m++) af[m] = *(bf16x8*)&As[(wrow + m*16 + l15)*40 + l16*8];
    #pragma unroll
    for (int n = 0; n < 4; n++) bg[n] = *(bf16x8*)&Bs[(wcol + n*16 + l15)*40 + l16*8];
    #pragma unroll
    for (int m = 0; m < MREP; m++)
      #pragma unroll
      for (int n = 0; n < 4; n++)
        acc[m][n] = __builtin_amdgcn_mfma_f32_16x16x32_bf16(af[m], bg[n], acc[m][n], 0, 0, 0);
    __syncthreads();
  }
  #pragma unroll
  for (int m = 0; m < MREP; m++){
    #pragma unroll
    for (int n = 0; n < 4; n++){
      int gcol = wcol + n*16 + l15;
      #pragma unroll
      for (int i = 0; i < 4; i++){
        int grow = row0 + wrow + m*16 + l16*4 + i;
        if (grow < M)
          C[(size_t)grow*NOUT + gcol] = acc[m][n][i];
      }
    }
  }
}

// ---------------- aggregation (CSR, per node; bf16 outputs) ----------------
__global__ void k_aggregate(const int* __restrict__ offs, const int* __restrict__ ssrc,
    const short* __restrict__ ea_s,
    const float* __restrict__ t_d, const float* __restrict__ t_s,
    const float* __restrict__ WeL, const float* __restrict__ bL,
    short* __restrict__ mean, short* __restrict__ mn, short* __restrict__ mx,
    short* __restrict__ stdv, int fi){
  int tid = threadIdx.x;
  int npb = blockDim.x / fi;
  int local = tid / fi, f = tid % fi;
  int n = blockIdx.x * npb + local;
  if (n >= NN) return;
  float wreg[13];
  #pragma unroll
  for (int r = 0; r < 13; r++) wreg[r] = WeL[r*fi + f];
  float base = t_d[(size_t)n*fi + f] + bL[f];
  int e0 = offs[n], e1 = offs[n+1];
  float s = 0.f, s2 = 0.f, vmn = FLT_MAX, vmx = -FLT_MAX;
  for (int p = e0; p < e1; p++){
    int src = ssrc[p];
    const bf16x8* er = (const bf16x8*)(ea_s + (size_t)p*16);
    bf16x8 ev0 = er[0], ev1 = er[1];
    float m = base + t_s[(size_t)src*fi + f];
    #pragma unroll
    for (int r = 0; r < 8; r++) m += bf2f(ev0[r]) * wreg[r];
    #pragma unroll
    for (int r = 0; r < 5; r++) m += bf2f(ev1[r]) * wreg[8 + r];
    s += m; s2 += m*m;
    vmn = fminf(vmn, m); vmx = fmaxf(vmx, m);
  }
  int c = e1 - e0;
  float denom = fmaxf((float)c, 1.f);
  float me = s/denom, me2 = s2/denom;
  float sd = sqrtf(fmaxf(me2 - me*me, 0.f) + 1e-5f);
  size_t o = (size_t)n*fi + f;
  mean[o] = f2bf(me);
  stdv[o] = f2bf(sd);
  mn[o] = (c > 0) ? f2bf(vmn) : 0;
  mx[o] = (c > 0) ? f2bf(vmx) : 0;
}

// ---------------- BatchNorm ----------------
__global__ void k_bn_reduce(const float* __restrict__ x, float* __restrict__ sums, int fo, int rows){
  __shared__ float sh[512];
  int tid = threadIdx.x;
  int col = tid % fo, grp = tid / fo, ngrp = 256 / fo;
  float s = 0.f, s2 = 0.f;
  int r0 = blockIdx.x * rows;
  int rend = min(r0 + rows, NN);
  for (int r = r0 + grp; r < rend; r += ngrp){
    float v = x[(size_t)r*fo + col];
    s += v; s2 += v*v;
  }
  sh[tid] = s; sh[256 + tid] = s2;
  __syncthreads();
  if (grp == 0){
    for (int g = 1; g < ngrp; g++){ s += sh[g*fo + col]; s2 += sh[256 + g*fo + col]; }
    atomicAdd(&sums[col], s);
    atomicAdd(&sums[fo + col], s2);
  }
}

// reads fp32 z-out, writes bf16 activations only
__global__ void k_bn_apply(const float* __restrict__ x, const float* __restrict__ sums,
                           const float* __restrict__ g, const float* __restrict__ b,
                           short* __restrict__ xbf, int fo, int total){
  int i = blockIdx.x*blockDim.x + threadIdx.x;
  if (i >= total) return;
  int col = i % fo;
  float mu = sums[col] / (float)NN;
  float var = sums[fo + col] / (float)NN - mu*mu;
  float v = (x[i] - mu) * rsqrtf(var + 1e-5f) * g[col] + b[col];
  xbf[i] = f2bf(fmaxf(v, 0.f));
}

// ---------------- host ----------------
extern "C" void kernel_launch(void* const* d_in, const int* in_sizes, int n_in,
                              void* d_out, int out_size, void* d_ws, size_t ws_size,
                              hipStream_t stream){
  const float* x0 = (const float*)d_in[0];
  const int*   ei = (const int*)d_in[1];
  const float* ea = (const float*)d_in[2];
  const float* W[35];
  for (int i = 0; i < 35; i++) W[i] = (const float*)d_in[i];
  const float* wc = W[33];
  const float* bc = W[34];

  char* w = (char*)d_ws;
  auto alloc = [&](size_t bytes)->void*{
    void* p = (void*)w; w += (bytes + 255) & ~(size_t)255; return p;
  };
  int* cnt    = (int*)alloc((size_t)NN*4);
  int* offs   = (int*)alloc((size_t)(NN+1)*4);
  int* cursor = (int*)alloc((size_t)NN*4);
  int* totals = (int*)alloc(64*4);
  int* ssrc   = (int*)alloc((size_t)NE*4);
  int* seid   = (int*)alloc((size_t)NE*4);
  float* sumlog = (float*)alloc(256);
  float* r1   = (float*)alloc((size_t)NN*4);
  float* r2   = (float*)alloc((size_t)NN*4);
  float* bns  = (float*)alloc(512*4);
  float* WeL  = (float*)alloc(13*128*4);
  float* bL   = (float*)alloc(128*4);
  short* WolT = (short*)alloc((size_t)256*1664*2);
  short* wpT  = (short*)alloc((size_t)2*128*128*2);
  short* wcT  = (short*)alloc((size_t)10*256*2);
  short* ea_s = (short*)alloc((size_t)NE*16*2);       // bf16, CSR-permuted, padded to 16
  short* agg[4];
  for (int a = 0; a < 4; a++) agg[a] = (short*)alloc((size_t)NN*128*2);
  float* F    = (float*)alloc((size_t)NN*256*4);      // t_d/t_s alias z-out
  short* xbfA = (short*)alloc((size_t)NN*128*2);      // L1 in (fi=32), L3 in (fi=128)
  short* xbfB = (short*)alloc((size_t)NN*256*2);      // L2 in (fi=64), classifier in (256)

  hipMemsetAsync(cnt, 0, (size_t)NN*4, stream);
  hipMemsetAsync(sumlog, 0, 4, stream);
  k_count<<<(NE+255)/256, 256, 0, stream>>>(ei + NE, cnt);
  k_scan_part<<<49, 1024, 0, stream>>>(cnt, offs, totals);
  k_scan_tops<<<1, 64, 0, stream>>>(totals, 49);
  k_scan_add<<<(NN+256)/256, 256, 0, stream>>>(offs, totals, cursor);
  k_scatter<<<(NE+255)/256, 256, 0, stream>>>(ei, cursor, ssrc, seid);
  k_permute_ea<<<(NE*16+255)/256, 256, 0, stream>>>(ea, seid, ea_s);
  k_sumlog<<<256, 256, 0, stream>>>(cnt, sumlog);
  k_rscale<<<(NN+255)/256, 256, 0, stream>>>(cnt, sumlog, r1, r2);
  k_prep_wcT<<<10, 256, 0, stream>>>(wc, wcT);
  k_f2bf_arr<<<(NN*32+255)/256, 256, 0, stream>>>(x0, xbfA, NN*32);

  const short* xin = xbfA;
  const int fis[3] = {32, 64, 128};
  const int GX = (NN + 63) / 64;
  const int GB = (NN + 255) / 256;
  for (int l = 0; l < 3; l++){
    int fi = fis[l], fo = 2*fi;
    const float* we = W[3+10*l+0], *be = W[3+10*l+1];
    const float* wp = W[3+10*l+2], *bp = W[3+10*l+3];
    const float* wo = W[3+10*l+4];
    const float* wl = W[3+10*l+6];
    const float* g  = W[3+10*l+8], *bb = W[3+10*l+9];

    float* t_d = F;                          // [NN, fi]
    float* t_s = F + (size_t)NN*fi;          // [NN, fi]

    k_prep_edge<<<(14*fi+255)/256, 256, 0, stream>>>(we, be, wp, bp, WeL, bL, fi);
    k_prep_wolT<<<13*fi, fo, 0, stream>>>(wo, wl, WolT, fo, 13*fi);
    k_prep_wpT<<<(2*fi*fi+255)/256, 256, 0, stream>>>(wp, wpT, fi);

    dim3 gt(GX, (fi + 63) / 64);
    k_mfma<<<gt, 256, 0, stream>>>(NN, fi, fi, fi, xin, xin, xin, xin, xin,
        r1, r2, wpT, fi, t_d, fi, nullptr);
    k_mfma<<<gt, 256, 0, stream>>>(NN, fi, fi, fi, xin, xin, xin, xin, xin,
        r1, r2, wpT + (size_t)fi*fi, fi, t_s, fi, nullptr);

    int bs = (fi < 64) ? 64 : fi;
    int npb = bs / fi;
    k_aggregate<<<(NN+npb-1)/npb, bs, 0, stream>>>(offs, ssrc, ea_s, t_d, t_s,
        WeL, bL, agg[0], agg[1], agg[2], agg[3], fi);

    // z-GEMM: big tile, full-N per block; writes F (t_d/t_s dead)
    if (l == 0)
      k_mfma_big<2><<<GB, 512, 0, stream>>>(NN, 13*fi, fi, xin, agg[0], agg[1], agg[2], agg[3],
          r1, r2, WolT, F);
    else if (l == 1)
      k_mfma_big<4><<<GB, 512, 0, stream>>>(NN, 13*fi, fi, xin, agg[0], agg[1], agg[2], agg[3],
          r1, r2, WolT, F);
    else
      k_mfma_big<8><<<GB, 512, 0, stream>>>(NN, 13*fi, fi, xin, agg[0], agg[1], agg[2], agg[3],
          r1, r2, WolT, F);

    short* xbf_next = (l == 0) ? xbfB : ((l == 1) ? xbfA : xbfB);
    hipMemsetAsync(bns, 0, (size_t)2*fo*4, stream);
    k_bn_reduce<<<256, 256, 0, stream>>>(F, bns, fo, (NN+255)/256);
    k_bn_apply<<<((NN*fo)+255)/256, 256, 0, stream>>>(F, bns, g, bb, xbf_next, fo, NN*fo);

    xin = xbf_next;
  }

  dim3 gc(GX, 1);
  k_mfma<<<gc, 256, 0, stream>>>(NN, 10, 256, 256, xin, xin, xin, xin, xin,
      r1, r2, wcT, 256, (float*)d_out, 10, bc);
}

// Round 6
// 961.183 us; speedup vs baseline: 3.4915x; 1.0452x over previous
//
#include <hip/hip_runtime.h>
#include <math.h>
#include <float.h>

#define NN 50000
#define NE 800000

typedef __attribute__((ext_vector_type(8))) short bf16x8;
typedef __attribute__((ext_vector_type(4))) float f32x4;

__device__ inline short f2bf(float f){
  union { float f; unsigned u; } v; v.f = f;
  unsigned u = v.u + 0x7FFFu + ((v.u >> 16) & 1u);
  return (short)(u >> 16);
}

__device__ inline float bf2f(short b){
  union { unsigned u; float f; } v;
  v.u = ((unsigned)(unsigned short)b) << 16;
  return v.f;
}

// ---------------- setup kernels ----------------

__global__ void k_count(const int* __restrict__ dst, int* __restrict__ cnt){
  int e = blockIdx.x*blockDim.x + threadIdx.x;
  if (e < NE) atomicAdd(&cnt[dst[e]], 1);
}

__global__ void k_scan_part(const int* __restrict__ cnt, int* __restrict__ offs, int* __restrict__ totals){
  __shared__ int sh[1024];
  int t = threadIdx.x, i = blockIdx.x*1024 + t;
  int v = (i < NN) ? cnt[i] : 0;
  sh[t] = v; __syncthreads();
  for (int off = 1; off < 1024; off <<= 1){
    int x = (t >= off) ? sh[t-off] : 0;
    __syncthreads();
    sh[t] += x;
    __syncthreads();
  }
  if (i < NN) offs[i] = sh[t] - v;
  if (t == 1023) totals[blockIdx.x] = sh[t];
}

__global__ void k_scan_tops(int* totals, int nb){
  if (threadIdx.x == 0){
    int acc = 0;
    for (int i = 0; i < nb; i++){ int v = totals[i]; totals[i] = acc; acc += v; }
  }
}

__global__ void k_scan_add(int* __restrict__ offs, const int* __restrict__ totals, int* __restrict__ cursor){
  int i = blockIdx.x*blockDim.x + threadIdx.x;
  if (i < NN){
    int v = offs[i] + totals[i >> 10];
    offs[i] = v;
    cursor[i] = v;
  } else if (i == NN){
    offs[NN] = NE;
  }
}

__global__ void k_scatter(const int* __restrict__ ei, int* __restrict__ cursor,
                          int* __restrict__ ssrc, int* __restrict__ seid){
  int e = blockIdx.x*blockDim.x + threadIdx.x;
  if (e >= NE) return;
  int d = ei[NE + e];
  int p = atomicAdd(&cursor[d], 1);
  ssrc[p] = ei[e];
  seid[p] = e;
}

// ea_s[p][0..15] = bf16(edge_attr[seid[p]][0..12]), padded with 0
__global__ void k_permute_ea(const float* __restrict__ ea, const int* __restrict__ seid,
                             short* __restrict__ ea_s){
  int i = blockIdx.x*blockDim.x + threadIdx.x;
  if (i >= NE*16) return;
  int p = i >> 4, r = i & 15;
  int eid = seid[p];
  float v = (r < 13) ? ea[(size_t)eid*13 + r] : 0.f;
  ea_s[i] = f2bf(v);
}

__global__ void k_sumlog(const int* __restrict__ cnt, float* __restrict__ sumlog){
  __shared__ float sh[256];
  int t = threadIdx.x;
  float s = 0.f;
  for (int i = blockIdx.x*256 + t; i < NN; i += gridDim.x*256)
    s += logf((float)cnt[i] + 1.f);
  sh[t] = s; __syncthreads();
  for (int o = 128; o > 0; o >>= 1){ if (t < o) sh[t] += sh[t+o]; __syncthreads(); }
  if (t == 0) atomicAdd(sumlog, sh[0]);
}

__global__ void k_rscale(const int* __restrict__ cnt, const float* __restrict__ sumlog,
                         float* __restrict__ r1, float* __restrict__ r2){
  int i = blockIdx.x*blockDim.x + threadIdx.x;
  if (i >= NN) return;
  float avg = sumlog[0] / (float)NN;
  float logd = logf(fmaxf((float)cnt[i], 1.f) + 1.f);
  r1[i] = logd / avg;
  r2[i] = avg / logd;
}

// fp32 -> bf16 array convert
__global__ void k_f2bf_arr(const float* __restrict__ in, short* __restrict__ out, int n){
  int i = blockIdx.x*blockDim.x + threadIdx.x;
  if (i < n) out[i] = f2bf(in[i]);
}

// ---------------- per-layer weight prep ----------------

// WeLT[f][k] = bf16( (we @ wp_bot)[k][f] ), k<13; zero for k in [13,32)
__global__ void k_prep_welt(const float* __restrict__ we, const float* __restrict__ wp,
                            short* __restrict__ WeLT, int fi){
  int idx = blockIdx.x*blockDim.x + threadIdx.x;
  if (idx >= fi*32) return;
  int f = idx >> 5, k = idx & 31;
  float s = 0.f;
  if (k < 13){
    const float* wpb = wp + (size_t)2*fi*fi;
    const float* wr = we + k*fi;
    for (int j = 0; j < fi; j++) s += wr[j] * wpb[(size_t)j*fi + f];
  }
  WeLT[idx] = f2bf(s);
}

// bL[f] = bp[f] + be @ wp_bot[:,f]
__global__ void k_prep_bl(const float* __restrict__ be, const float* __restrict__ wp,
                          const float* __restrict__ bp, float* __restrict__ bL, int fi){
  int f = blockIdx.x*blockDim.x + threadIdx.x;
  if (f >= fi) return;
  const float* wpb = wp + (size_t)2*fi*fi;
  float s = bp[f];
  for (int j = 0; j < fi; j++) s += be[j] * wpb[(size_t)j*fi + f];
  bL[f] = s;
}

// WolT[o][k] = bf16( (wo @ wl)[k][o] )
__global__ void k_prep_wolT(const float* __restrict__ wo, const float* __restrict__ wl,
                            short* __restrict__ WolT, int fo, int K13){
  int k = blockIdx.x;
  int o = threadIdx.x;
  float s = 0.f;
  for (int j = 0; j < fo; j++) s += wo[(size_t)k*fo + j] * wl[(size_t)j*fo + o];
  WolT[(size_t)o*K13 + k] = f2bf(s);
}

// wpT[s][f][j] = bf16( wp[(s*fi + j)][f] )
__global__ void k_prep_wpT(const float* __restrict__ wp, short* __restrict__ wpT, int fi){
  int idx = blockIdx.x*blockDim.x + threadIdx.x;
  if (idx >= 2*fi*fi) return;
  int s = idx/(fi*fi), rem = idx - s*fi*fi;
  int f = rem/fi, j = rem - f*fi;
  wpT[idx] = f2bf(wp[((size_t)s*fi + j)*fi + f]);
}

// wcT[c][k] = bf16(wc[k][c])
__global__ void k_prep_wcT(const float* __restrict__ wc, short* __restrict__ wcT){
  int idx = blockIdx.x*blockDim.x + threadIdx.x;
  if (idx >= 2560) return;
  int c = idx >> 8, k = idx & 255;
  wcT[idx] = f2bf(wc[k*10 + c]);
}

// ---------------- plain bf16 GEMM, bf16 out, fp32 bias (for t_d/t_s) -------
__global__ __launch_bounds__(256) void k_gemm_t(int M, int Nout, int K,
    const short* __restrict__ A, const short* __restrict__ BT,
    const float* __restrict__ bias, short* __restrict__ Cb)
{
  __shared__ short As[64*40];
  __shared__ short Bs[64*40];
  int tid = threadIdx.x;
  int lane = tid & 63, w = tid >> 6;
  int wr = w >> 1, wc = w & 1;
  int l15 = lane & 15, l16 = lane >> 4;
  int row0 = blockIdx.x*64, col0 = blockIdx.y*64;
  int sr = tid >> 2, sq = tid & 3;
  f32x4 acc[2][2] = {};
  for (int k0 = 0; k0 < K; k0 += 32){
    int gr = row0 + sr;
    bf16x8 av = {0,0,0,0,0,0,0,0};
    if (gr < M) av = *(const bf16x8*)(A + (size_t)gr*K + k0 + sq*8);
    *(bf16x8*)&As[sr*40 + sq*8] = av;
    int gc = col0 + sr;
    bf16x8 bv = {0,0,0,0,0,0,0,0};
    if (gc < Nout) bv = *(const bf16x8*)(BT + (size_t)gc*K + k0 + sq*8);
    *(bf16x8*)&Bs[sr*40 + sq*8] = bv;
    __syncthreads();
    bf16x8 af[2], bg[2];
    #pragma unroll
    for (int m = 0; m < 2; m++) af[m] = *(bf16x8*)&As[(wr*32 + m*16 + l15)*40 + l16*8];
    #pragma unroll
    for (int n = 0; n < 2; n++) bg[n] = *(bf16x8*)&Bs[(wc*32 + n*16 + l15)*40 + l16*8];
    #pragma unroll
    for (int m = 0; m < 2; m++)
      #pragma unroll
      for (int n = 0; n < 2; n++)
        acc[m][n] = __builtin_amdgcn_mfma_f32_16x16x32_bf16(af[m], bg[n], acc[m][n], 0, 0, 0);
    __syncthreads();
  }
  #pragma unroll
  for (int m = 0; m < 2; m++){
    #pragma unroll
    for (int n = 0; n < 2; n++){
      int gcol = col0 + wc*32 + n*16 + l15;
      #pragma unroll
      for (int i = 0; i < 4; i++){
        int grow = row0 + wr*32 + m*16 + l16*4 + i;
        if (grow < M && gcol < Nout)
          Cb[(size_t)grow*Nout + gcol] = f2bf(acc[m][n][i] + (bias ? bias[gcol] : 0.f));
      }
    }
  }
}

// ---------------- MFMA GEMM (64x64 tile, bf16 A sources, fp32 C) -----------
// Used for classifier. A = P0 (FI=K).
__global__ __launch_bounds__(256) void k_mfma(int M, int Nout, int K, int FI,
    const short* __restrict__ P0, const short* __restrict__ P1,
    const short* __restrict__ P2, const short* __restrict__ P3,
    const short* __restrict__ P4,
    const float* __restrict__ r1, const float* __restrict__ r2,
    const short* __restrict__ BT, int ldbt,
    float* __restrict__ C, int ldc, const float* __restrict__ bias)
{
  __shared__ short As[64*40];
  __shared__ short Bs[64*40];
  const short* Pt[5] = {P0, P1, P2, P3, P4};
  int tid = threadIdx.x;
  int lane = tid & 63, w = tid >> 6;
  int wr = w >> 1, wc = w & 1;
  int l15 = lane & 15, l16 = lane >> 4;
  int row0 = blockIdx.x*64, col0 = blockIdx.y*64;
  int sr = tid >> 2, sq = tid & 3;
  f32x4 acc[2][2] = {};
  for (int k0 = 0; k0 < K; k0 += 32){
    int kb = k0 / FI;
    int pi = (kb == 0) ? 0 : ((kb - 1) & 3) + 1;
    int sm = (kb == 0) ? 0 : ((kb - 1) >> 2);
    const short* __restrict__ P = Pt[pi];
    int j0 = k0 - kb*FI + sq*8;
    int gr = row0 + sr;
    bf16x8 av = {0,0,0,0,0,0,0,0};
    if (gr < M){
      av = *(const bf16x8*)(P + (size_t)gr*FI + j0);
      if (sm){
        float s = (sm == 1) ? r1[gr] : r2[gr];
        #pragma unroll
        for (int e = 0; e < 8; e++) av[e] = f2bf(bf2f(av[e]) * s);
      }
    }
    *(bf16x8*)&As[sr*40 + sq*8] = av;
    int gc = col0 + sr;
    bf16x8 bv = {0,0,0,0,0,0,0,0};
    if (gc < Nout)
      bv = *(const bf16x8*)(BT + (size_t)gc*ldbt + k0 + sq*8);
    *(bf16x8*)&Bs[sr*40 + sq*8] = bv;
    __syncthreads();
    bf16x8 af[2], bg[2];
    #pragma unroll
    for (int m = 0; m < 2; m++) af[m] = *(bf16x8*)&As[(wr*32 + m*16 + l15)*40 + l16*8];
    #pragma unroll
    for (int n = 0; n < 2; n++) bg[n] = *(bf16x8*)&Bs[(wc*32 + n*16 + l15)*40 + l16*8];
    #pragma unroll
    for (int m = 0; m < 2; m++)
      #pragma unroll
      for (int n = 0; n < 2; n++)
        acc[m][n] = __builtin_amdgcn_mfma_f32_16x16x32_bf16(af[m], bg[n], acc[m][n], 0, 0, 0);
    __syncthreads();
  }
  #pragma unroll
  for (int m = 0; m < 2; m++){
    #pragma unroll
    for (int n = 0; n < 2; n++){
      int gcol = col0 + wc*32 + n*16 + l15;
      #pragma unroll
      for (int i = 0; i < 4; i++){
        int grow = row0 + wr*32 + m*16 + l16*4 + i;
        if (grow < M && gcol < Nout)
          C[(size_t)grow*ldc + gcol] = acc[m][n][i] + (bias ? bias[gcol] : 0.f);
      }
    }
  }
}

// ---------------- big-tile MFMA GEMM: 256 rows x full-N, 512 threads -------
template<int MREP>
__global__ __launch_bounds__(512) void k_mfma_big(int M, int K, int FI,
    const short* __restrict__ P0, const short* __restrict__ P1,
    const short* __restrict__ P2, const short* __restrict__ P3,
    const short* __restrict__ P4,
    const float* __restrict__ r1, const float* __restrict__ r2,
    const short* __restrict__ BT,
    float* __restrict__ C)
{
  constexpr int WCG = MREP/2;          // wave col groups (Nout/64)
  constexpr int NOUT = WCG*64;
  __shared__ short As[256*40];
  __shared__ short Bs[256*40];         // only NOUT*40 used
  const short* Pt[5] = {P0, P1, P2, P3, P4};
  int tid = threadIdx.x;
  int lane = tid & 63, w = tid >> 6;
  int wid_c = w % WCG, wid_r = w / WCG;
  int wrow = wid_r * (MREP*16);
  int wcol = wid_c * 64;
  int l15 = lane & 15, l16 = lane >> 4;
  int row0 = blockIdx.x*256;
  int trow = tid >> 1, tseg = tid & 1;
  f32x4 acc[MREP][4] = {};
  for (int k0 = 0; k0 < K; k0 += 32){
    int kb = k0 / FI;
    int pi = (kb == 0) ? 0 : ((kb - 1) & 3) + 1;
    int sm = (kb == 0) ? 0 : ((kb - 1) >> 2);
    const short* __restrict__ P = Pt[pi];
    int j0 = k0 - kb*FI + tseg*16;
    int gr = row0 + trow;
    bf16x8 a0 = {0,0,0,0,0,0,0,0}, a1 = a0;
    if (gr < M){
      const short* src = P + (size_t)gr*FI + j0;
      a0 = *(const bf16x8*)src;
      a1 = *(const bf16x8*)(src + 8);
      if (sm){
        float s = (sm == 1) ? r1[gr] : r2[gr];
        #pragma unroll
        for (int e = 0; e < 8; e++){ a0[e] = f2bf(bf2f(a0[e])*s); a1[e] = f2bf(bf2f(a1[e])*s); }
      }
    }
    *(bf16x8*)&As[trow*40 + tseg*16] = a0;
    *(bf16x8*)&As[trow*40 + tseg*16 + 8] = a1;
    if (trow < NOUT){
      const short* src = BT + (size_t)trow*K + k0 + tseg*16;
      *(bf16x8*)&Bs[trow*40 + tseg*16]     = *(const bf16x8*)src;
      *(bf16x8*)&Bs[trow*40 + tseg*16 + 8] = *(const bf16x8*)(src + 8);
    }
    __syncthreads();
    bf16x8 af[MREP], bg[4];
    #pragma unroll
    for (int m = 0; m < MREP; m++) af[m] = *(bf16x8*)&As[(wrow + m*16 + l15)*40 + l16*8];
    #pragma unroll
    for (int n = 0; n < 4; n++) bg[n] = *(bf16x8*)&Bs[(wcol + n*16 + l15)*40 + l16*8];
    #pragma unroll
    for (int m = 0; m < MREP; m++)
      #pragma unroll
      for (int n = 0; n < 4; n++)
        acc[m][n] = __builtin_amdgcn_mfma_f32_16x16x32_bf16(af[m], bg[n], acc[m][n], 0, 0, 0);
    __syncthreads();
  }
  #pragma unroll
  for (int m = 0; m < MREP; m++){
    #pragma unroll
    for (int n = 0; n < 4; n++){
      int gcol = wcol + n*16 + l15;
      #pragma unroll
      for (int i = 0; i < 4; i++){
        int grow = row0 + wrow + m*16 + l16*4 + i;
        if (grow < M)
          C[(size_t)grow*NOUT + gcol] = acc[m][n][i];
      }
    }
  }
}

// ---------------- MFMA aggregation: one wave per node ----------------------
// em = ea_s(16 edges x K32) @ WeLT -> C[row=edge slot=(l>>4)*4+i][col=feat=l&15]
// m = em + t_d[n][f](incl bL) + t_s[src][f]; masked stats; xor16/32 reduce;
// lane-group l16 stores {mean, min, max, std}.
template<int NC>   // NC = fi/16
__global__ __launch_bounds__(256) void k_agg_mfma(
    const int* __restrict__ offs, const int* __restrict__ ssrc,
    const short* __restrict__ ea_s,      // [NE+16][16] bf16 CSR order
    const short* __restrict__ t_d,       // [NN][fi] bf16 (bL fused)
    const short* __restrict__ t_s,       // [NN][fi] bf16
    const short* __restrict__ WeLT,      // [fi][32] bf16, rows k>=13 zero
    short* __restrict__ mean, short* __restrict__ mn,
    short* __restrict__ mx,  short* __restrict__ stdv)
{
  constexpr int FI = NC*16;
  int n = (blockIdx.x*blockDim.x + threadIdx.x) >> 6;
  int lane = threadIdx.x & 63;
  int l15 = lane & 15, l16 = lane >> 4;
  if (n >= NN) return;
  bf16x8 bfrag[NC];
  #pragma unroll
  for (int c = 0; c < NC; c++)
    bfrag[c] = *(const bf16x8*)(WeLT + (size_t)(c*16 + l15)*32 + l16*8);
  float base[NC];
  #pragma unroll
  for (int c = 0; c < NC; c++)
    base[c] = bf2f(t_d[(size_t)n*FI + c*16 + l15]);
  float s[NC], s2[NC], vmn[NC], vmx[NC];
  #pragma unroll
  for (int c = 0; c < NC; c++){ s[c]=0.f; s2[c]=0.f; vmn[c]=FLT_MAX; vmx[c]=-FLT_MAX; }
  int e0 = offs[n], e1 = offs[n+1];
  for (int p0 = e0; p0 < e1; p0 += 16){
    int pa = p0 + l15; if (pa > e1-1) pa = e1-1;
    bf16x8 afrag = *(const bf16x8*)(ea_s + (size_t)pa*16 + l16*8);
    int prow[4], srcr[4];
    #pragma unroll
    for (int i = 0; i < 4; i++){
      int pp = p0 + l16*4 + i;
      prow[i] = pp;
      int pc = (pp > e1-1) ? e1-1 : pp;
      srcr[i] = ssrc[pc];
    }
    #pragma unroll
    for (int c = 0; c < NC; c++){
      f32x4 acc = {0.f,0.f,0.f,0.f};
      acc = __builtin_amdgcn_mfma_f32_16x16x32_bf16(afrag, bfrag[c], acc, 0, 0, 0);
      #pragma unroll
      for (int i = 0; i < 4; i++){
        float tv = bf2f(t_s[(size_t)srcr[i]*FI + c*16 + l15]);
        float m = acc[i] + base[c] + tv;
        bool valid = prow[i] < e1;
        float mv = valid ? m : 0.f;
        s[c] += mv;
        s2[c] = fmaf(mv, mv, s2[c]);
        vmn[c] = fminf(vmn[c], valid ? m :  FLT_MAX);
        vmx[c] = fmaxf(vmx[c], valid ? m : -FLT_MAX);
      }
    }
  }
  int cdeg = e1 - e0;
  float denom = fmaxf((float)cdeg, 1.f);
  short* outp = (l16==0) ? mean : (l16==1) ? mn : (l16==2) ? mx : stdv;
  #pragma unroll
  for (int c = 0; c < NC; c++){
    float sv = s[c];   sv  += __shfl_xor(sv, 16, 64);  sv  += __shfl_xor(sv, 32, 64);
    float s2v = s2[c]; s2v += __shfl_xor(s2v, 16, 64); s2v += __shfl_xor(s2v, 32, 64);
    float mnv = vmn[c]; mnv = fminf(mnv, __shfl_xor(mnv, 16, 64)); mnv = fminf(mnv, __shfl_xor(mnv, 32, 64));
    float mxv = vmx[c]; mxv = fmaxf(mxv, __shfl_xor(mxv, 16, 64)); mxv = fmaxf(mxv, __shfl_xor(mxv, 32, 64));
    float me = sv/denom, me2 = s2v/denom;
    float sd = sqrtf(fmaxf(me2 - me*me, 0.f) + 1e-5f);
    float val = (l16==0) ? me : (l16==1) ? (cdeg>0 ? mnv : 0.f)
              : (l16==2) ? (cdeg>0 ? mxv : 0.f) : sd;
    outp[(size_t)n*FI + c*16 + l15] = f2bf(val);
  }
}

// ---------------- BatchNorm ----------------
__global__ void k_bn_reduce(const float* __restrict__ x, float* __restrict__ sums, int fo, int rows){
  __shared__ float sh[512];
  int tid = threadIdx.x;
  int col = tid % fo, grp = tid / fo, ngrp = 256 / fo;
  float s = 0.f, s2 = 0.f;
  int r0 = blockIdx.x * rows;
  int rend = min(r0 + rows, NN);
  for (int r = r0 + grp; r < rend; r += ngrp){
    float v = x[(size_t)r*fo + col];
    s += v; s2 += v*v;
  }
  sh[tid] = s; sh[256 + tid] = s2;
  __syncthreads();
  if (grp == 0){
    for (int g = 1; g < ngrp; g++){ s += sh[g*fo + col]; s2 += sh[256 + g*fo + col]; }
    atomicAdd(&sums[col], s);
    atomicAdd(&sums[fo + col], s2);
  }
}

__global__ void k_bn_apply(const float* __restrict__ x, const float* __restrict__ sums,
                           const float* __restrict__ g, const float* __restrict__ b,
                           short* __restrict__ xbf, int fo, int total){
  int i = blockIdx.x*blockDim.x + threadIdx.x;
  if (i >= total) return;
  int col = i % fo;
  float mu = sums[col] / (float)NN;
  float var = sums[fo + col] / (float)NN - mu*mu;
  float v = (x[i] - mu) * rsqrtf(var + 1e-5f) * g[col] + b[col];
  xbf[i] = f2bf(fmaxf(v, 0.f));
}

// ---------------- host ----------------
extern "C" void kernel_launch(void* const* d_in, const int* in_sizes, int n_in,
                              void* d_out, int out_size, void* d_ws, size_t ws_size,
                              hipStream_t stream){
  const float* x0 = (const float*)d_in[0];
  const int*   ei = (const int*)d_in[1];
  const float* ea = (const float*)d_in[2];
  const float* W[35];
  for (int i = 0; i < 35; i++) W[i] = (const float*)d_in[i];
  const float* wc = W[33];
  const float* bc = W[34];

  char* w = (char*)d_ws;
  auto alloc = [&](size_t bytes)->void*{
    void* p = (void*)w; w += (bytes + 255) & ~(size_t)255; return p;
  };
  int* cnt    = (int*)alloc((size_t)NN*4);
  int* offs   = (int*)alloc((size_t)(NN+1)*4);
  int* cursor = (int*)alloc((size_t)NN*4);
  int* totals = (int*)alloc(64*4);
  int* ssrc   = (int*)alloc((size_t)NE*4);
  int* seid   = (int*)alloc((size_t)NE*4);
  float* sumlog = (float*)alloc(256);
  float* r1   = (float*)alloc((size_t)NN*4);
  float* r2   = (float*)alloc((size_t)NN*4);
  float* bns  = (float*)alloc(512*4);
  float* bL   = (float*)alloc(128*4);
  short* WeLT = (short*)alloc((size_t)128*32*2);
  short* WolT = (short*)alloc((size_t)256*1664*2);
  short* wpT  = (short*)alloc((size_t)2*128*128*2);
  short* wcT  = (short*)alloc((size_t)10*256*2);
  short* ea_s = (short*)alloc((size_t)(NE+16)*16*2);  // bf16, CSR-permuted, padded
  short* agg[4];
  for (int a = 0; a < 4; a++) agg[a] = (short*)alloc((size_t)NN*128*2);
  float* F    = (float*)alloc((size_t)NN*256*4);      // z-out fp32; t_d/t_s bf16 alias
  short* xbfA = (short*)alloc((size_t)NN*128*2);
  short* xbfB = (short*)alloc((size_t)NN*256*2);

  hipMemsetAsync(cnt, 0, (size_t)NN*4, stream);
  hipMemsetAsync(sumlog, 0, 4, stream);
  k_count<<<(NE+255)/256, 256, 0, stream>>>(ei + NE, cnt);
  k_scan_part<<<49, 1024, 0, stream>>>(cnt, offs, totals);
  k_scan_tops<<<1, 64, 0, stream>>>(totals, 49);
  k_scan_add<<<(NN+256)/256, 256, 0, stream>>>(offs, totals, cursor);
  k_scatter<<<(NE+255)/256, 256, 0, stream>>>(ei, cursor, ssrc, seid);
  k_permute_ea<<<(NE*16+255)/256, 256, 0, stream>>>(ea, seid, ea_s);
  k_sumlog<<<256, 256, 0, stream>>>(cnt, sumlog);
  k_rscale<<<(NN+255)/256, 256, 0, stream>>>(cnt, sumlog, r1, r2);
  k_prep_wcT<<<10, 256, 0, stream>>>(wc, wcT);
  k_f2bf_arr<<<(NN*32+255)/256, 256, 0, stream>>>(x0, xbfA, NN*32);

  const short* xin = xbfA;
  const int fis[3] = {32, 64, 128};
  const int GX = (NN + 63) / 64;
  const int GB = (NN + 255) / 256;
  const int GA = (NN*64 + 255) / 256;   // one wave per node
  for (int l = 0; l < 3; l++){
    int fi = fis[l], fo = 2*fi;
    const float* we = W[3+10*l+0], *be = W[3+10*l+1];
    const float* wp = W[3+10*l+2], *bp = W[3+10*l+3];
    const float* wo = W[3+10*l+4];
    const float* wl = W[3+10*l+6];
    const float* g  = W[3+10*l+8], *bb = W[3+10*l+9];

    short* t_d = (short*)F;                  // [NN, fi] bf16 — dead before F rewritten
    short* t_s = (short*)F + (size_t)NN*fi;  // [NN, fi] bf16

    k_prep_welt<<<(fi*32+255)/256, 256, 0, stream>>>(we, wp, WeLT, fi);
    k_prep_bl<<<(fi+127)/128, 128, 0, stream>>>(be, wp, bp, bL, fi);
    k_prep_wolT<<<13*fi, fo, 0, stream>>>(wo, wl, WolT, fo, 13*fi);
    k_prep_wpT<<<(2*fi*fi+255)/256, 256, 0, stream>>>(wp, wpT, fi);

    dim3 gt(GX, (fi + 63) / 64);
    k_gemm_t<<<gt, 256, 0, stream>>>(NN, fi, fi, xin, wpT, bL, t_d);
    k_gemm_t<<<gt, 256, 0, stream>>>(NN, fi, fi, xin, wpT + (size_t)fi*fi, nullptr, t_s);

    if (l == 0)
      k_agg_mfma<2><<<GA, 256, 0, stream>>>(offs, ssrc, ea_s, t_d, t_s, WeLT,
          agg[0], agg[1], agg[2], agg[3]);
    else if (l == 1)
      k_agg_mfma<4><<<GA, 256, 0, stream>>>(offs, ssrc, ea_s, t_d, t_s, WeLT,
          agg[0], agg[1], agg[2], agg[3]);
    else
      k_agg_mfma<8><<<GA, 256, 0, stream>>>(offs, ssrc, ea_s, t_d, t_s, WeLT,
          agg[0], agg[1], agg[2], agg[3]);

    if (l == 0)
      k_mfma_big<2><<<GB, 512, 0, stream>>>(NN, 13*fi, fi, xin, agg[0], agg[1], agg[2], agg[3],
          r1, r2, WolT, F);
    else if (l == 1)
      k_mfma_big<4><<<GB, 512, 0, stream>>>(NN, 13*fi, fi, xin, agg[0], agg[1], agg[2], agg[3],
          r1, r2, WolT, F);
    else
      k_mfma_big<8><<<GB, 512, 0, stream>>>(NN, 13*fi, fi, xin, agg[0], agg[1], agg[2], agg[3],
          r1, r2, WolT, F);

    short* xbf_next = (l == 0) ? xbfB : ((l == 1) ? xbfA : xbfB);
    hipMemsetAsync(bns, 0, (size_t)2*fo*4, stream);
    k_bn_reduce<<<256, 256, 0, stream>>>(F, bns, fo, (NN+255)/256);
    k_bn_apply<<<((NN*fo)+255)/256, 256, 0, stream>>>(F, bns, g, bb, xbf_next, fo, NN*fo);

    xin = xbf_next;
  }

  dim3 gc(GX, 1);
  k_mfma<<<gc, 256, 0, stream>>>(NN, 10, 256, 256, xin, xin, xin, xin, xin,
      r1, r2, wcT, 256, (float*)d_out, 10, bc);
}

// Round 7
// 918.081 us; speedup vs baseline: 3.6554x; 1.0469x over previous
//
#include <hip/hip_runtime.h>
#include <math.h>
#include <float.h>

#define NN 50000
#define NE 800000

typedef __attribute__((ext_vector_type(8))) short bf16x8;
typedef __attribute__((ext_vector_type(4))) float f32x4;

__device__ inline short f2bf(float f){
  union { float f; unsigned u; } v; v.f = f;
  unsigned u = v.u + 0x7FFFu + ((v.u >> 16) & 1u);
  return (short)(u >> 16);
}

__device__ inline float bf2f(short b){
  union { unsigned u; float f; } v;
  v.u = ((unsigned)(unsigned short)b) << 16;
  return v.f;
}

// ---------------- setup kernels ----------------

__global__ void k_count(const int* __restrict__ dst, int* __restrict__ cnt){
  int e = blockIdx.x*blockDim.x + threadIdx.x;
  if (e < NE) atomicAdd(&cnt[dst[e]], 1);
}

__global__ void k_scan_part(const int* __restrict__ cnt, int* __restrict__ offs, int* __restrict__ totals){
  __shared__ int sh[1024];
  int t = threadIdx.x, i = blockIdx.x*1024 + t;
  int v = (i < NN) ? cnt[i] : 0;
  sh[t] = v; __syncthreads();
  for (int off = 1; off < 1024; off <<= 1){
    int x = (t >= off) ? sh[t-off] : 0;
    __syncthreads();
    sh[t] += x;
    __syncthreads();
  }
  if (i < NN) offs[i] = sh[t] - v;
  if (t == 1023) totals[blockIdx.x] = sh[t];
}

__global__ void k_scan_tops(int* totals, int nb){
  if (threadIdx.x == 0){
    int acc = 0;
    for (int i = 0; i < nb; i++){ int v = totals[i]; totals[i] = acc; acc += v; }
  }
}

__global__ void k_scan_add(int* __restrict__ offs, const int* __restrict__ totals, int* __restrict__ cursor){
  int i = blockIdx.x*blockDim.x + threadIdx.x;
  if (i < NN){
    int v = offs[i] + totals[i >> 10];
    offs[i] = v;
    cursor[i] = v;
  } else if (i == NN){
    offs[NN] = NE;
  }
}

__global__ void k_scatter(const int* __restrict__ ei, int* __restrict__ cursor,
                          int* __restrict__ ssrc, int* __restrict__ seid){
  int e = blockIdx.x*blockDim.x + threadIdx.x;
  if (e >= NE) return;
  int d = ei[NE + e];
  int p = atomicAdd(&cursor[d], 1);
  ssrc[p] = ei[e];
  seid[p] = e;
}

// ea_s[p][0..15]: 0..12 = bf16(edge_attr[seid[p]]), 13 = 1.0 (t_d hook), 14,15 = 0
__global__ void k_permute_ea(const float* __restrict__ ea, const int* __restrict__ seid,
                             short* __restrict__ ea_s){
  int i = blockIdx.x*blockDim.x + threadIdx.x;
  if (i >= NE*16) return;
  int p = i >> 4, r = i & 15;
  int eid = seid[p];
  float v = (r < 13) ? ea[(size_t)eid*13 + r] : ((r == 13) ? 1.0f : 0.f);
  ea_s[i] = f2bf(v);
}

__global__ void k_sumlog(const int* __restrict__ cnt, float* __restrict__ sumlog){
  __shared__ float sh[256];
  int t = threadIdx.x;
  float s = 0.f;
  for (int i = blockIdx.x*256 + t; i < NN; i += gridDim.x*256)
    s += logf((float)cnt[i] + 1.f);
  sh[t] = s; __syncthreads();
  for (int o = 128; o > 0; o >>= 1){ if (t < o) sh[t] += sh[t+o]; __syncthreads(); }
  if (t == 0) atomicAdd(sumlog, sh[0]);
}

__global__ void k_rscale(const int* __restrict__ cnt, const float* __restrict__ sumlog,
                         float* __restrict__ r1, float* __restrict__ r2){
  int i = blockIdx.x*blockDim.x + threadIdx.x;
  if (i >= NN) return;
  float avg = sumlog[0] / (float)NN;
  float logd = logf(fmaxf((float)cnt[i], 1.f) + 1.f);
  r1[i] = logd / avg;
  r2[i] = avg / logd;
}

// fp32 -> bf16 array convert
__global__ void k_f2bf_arr(const float* __restrict__ in, short* __restrict__ out, int n){
  int i = blockIdx.x*blockDim.x + threadIdx.x;
  if (i < n) out[i] = f2bf(in[i]);
}

// ---------------- per-layer weight prep ----------------

// WeLT[f][k] = bf16( (we @ wp_bot)[k][f] ), k<13; zero for k in [13,32)
__global__ void k_prep_welt(const float* __restrict__ we, const float* __restrict__ wp,
                            short* __restrict__ WeLT, int fi){
  int idx = blockIdx.x*blockDim.x + threadIdx.x;
  if (idx >= fi*32) return;
  int f = idx >> 5, k = idx & 31;
  float s = 0.f;
  if (k < 13){
    const float* wpb = wp + (size_t)2*fi*fi;
    const float* wr = we + k*fi;
    for (int j = 0; j < fi; j++) s += wr[j] * wpb[(size_t)j*fi + f];
  }
  WeLT[idx] = f2bf(s);
}

// bL[f] = bp[f] + be @ wp_bot[:,f]
__global__ void k_prep_bl(const float* __restrict__ be, const float* __restrict__ wp,
                          const float* __restrict__ bp, float* __restrict__ bL, int fi){
  int f = blockIdx.x*blockDim.x + threadIdx.x;
  if (f >= fi) return;
  const float* wpb = wp + (size_t)2*fi*fi;
  float s = bp[f];
  for (int j = 0; j < fi; j++) s += be[j] * wpb[(size_t)j*fi + f];
  bL[f] = s;
}

// WolT[o][k] = bf16( (wo @ wl)[k][o] )
__global__ void k_prep_wolT(const float* __restrict__ wo, const float* __restrict__ wl,
                            short* __restrict__ WolT, int fo, int K13){
  int k = blockIdx.x;
  int o = threadIdx.x;
  float s = 0.f;
  for (int j = 0; j < fo; j++) s += wo[(size_t)k*fo + j] * wl[(size_t)j*fo + o];
  WolT[(size_t)o*K13 + k] = f2bf(s);
}

// wpT[s][f][j] = bf16( wp[(s*fi + j)][f] )
__global__ void k_prep_wpT(const float* __restrict__ wp, short* __restrict__ wpT, int fi){
  int idx = blockIdx.x*blockDim.x + threadIdx.x;
  if (idx >= 2*fi*fi) return;
  int s = idx/(fi*fi), rem = idx - s*fi*fi;
  int f = rem/fi, j = rem - f*fi;
  wpT[idx] = f2bf(wp[((size_t)s*fi + j)*fi + f]);
}

// wcT[c][k] = bf16(wc[k][c])
__global__ void k_prep_wcT(const float* __restrict__ wc, short* __restrict__ wcT){
  int idx = blockIdx.x*blockDim.x + threadIdx.x;
  if (idx >= 2560) return;
  int c = idx >> 8, k = idx & 255;
  wcT[idx] = f2bf(wc[k*10 + c]);
}

// ---------------- plain bf16 GEMM, bf16 out, fp32 bias (for t_d/t_s) -------
__global__ __launch_bounds__(256) void k_gemm_t(int M, int Nout, int K,
    const short* __restrict__ A, const short* __restrict__ BT,
    const float* __restrict__ bias, short* __restrict__ Cb)
{
  __shared__ short As[64*40];
  __shared__ short Bs[64*40];
  int tid = threadIdx.x;
  int lane = tid & 63, w = tid >> 6;
  int wr = w >> 1, wc = w & 1;
  int l15 = lane & 15, l16 = lane >> 4;
  int row0 = blockIdx.x*64, col0 = blockIdx.y*64;
  int sr = tid >> 2, sq = tid & 3;
  f32x4 acc[2][2] = {};
  for (int k0 = 0; k0 < K; k0 += 32){
    int gr = row0 + sr;
    bf16x8 av = {0,0,0,0,0,0,0,0};
    if (gr < M) av = *(const bf16x8*)(A + (size_t)gr*K + k0 + sq*8);
    *(bf16x8*)&As[sr*40 + sq*8] = av;
    int gc = col0 + sr;
    bf16x8 bv = {0,0,0,0,0,0,0,0};
    if (gc < Nout) bv = *(const bf16x8*)(BT + (size_t)gc*K + k0 + sq*8);
    *(bf16x8*)&Bs[sr*40 + sq*8] = bv;
    __syncthreads();
    bf16x8 af[2], bg[2];
    #pragma unroll
    for (int m = 0; m < 2; m++) af[m] = *(bf16x8*)&As[(wr*32 + m*16 + l15)*40 + l16*8];
    #pragma unroll
    for (int n = 0; n < 2; n++) bg[n] = *(bf16x8*)&Bs[(wc*32 + n*16 + l15)*40 + l16*8];
    #pragma unroll
    for (int m = 0; m < 2; m++)
      #pragma unroll
      for (int n = 0; n < 2; n++)
        acc[m][n] = __builtin_amdgcn_mfma_f32_16x16x32_bf16(af[m], bg[n], acc[m][n], 0, 0, 0);
    __syncthreads();
  }
  #pragma unroll
  for (int m = 0; m < 2; m++){
    #pragma unroll
    for (int n = 0; n < 2; n++){
      int gcol = col0 + wc*32 + n*16 + l15;
      #pragma unroll
      for (int i = 0; i < 4; i++){
        int grow = row0 + wr*32 + m*16 + l16*4 + i;
        if (grow < M && gcol < Nout)
          Cb[(size_t)grow*Nout + gcol] = f2bf(acc[m][n][i] + (bias ? bias[gcol] : 0.f));
      }
    }
  }
}

// ---------------- MFMA GEMM (64x64 tile, bf16 A, fp32 C) — classifier ------
__global__ __launch_bounds__(256) void k_mfma(int M, int Nout, int K,
    const short* __restrict__ A,
    const short* __restrict__ BT, int ldbt,
    float* __restrict__ C, int ldc, const float* __restrict__ bias)
{
  __shared__ short As[64*40];
  __shared__ short Bs[64*40];
  int tid = threadIdx.x;
  int lane = tid & 63, w = tid >> 6;
  int wr = w >> 1, wc = w & 1;
  int l15 = lane & 15, l16 = lane >> 4;
  int row0 = blockIdx.x*64, col0 = blockIdx.y*64;
  int sr = tid >> 2, sq = tid & 3;
  f32x4 acc[2][2] = {};
  for (int k0 = 0; k0 < K; k0 += 32){
    int gr = row0 + sr;
    bf16x8 av = {0,0,0,0,0,0,0,0};
    if (gr < M) av = *(const bf16x8*)(A + (size_t)gr*K + k0 + sq*8);
    *(bf16x8*)&As[sr*40 + sq*8] = av;
    int gc = col0 + sr;
    bf16x8 bv = {0,0,0,0,0,0,0,0};
    if (gc < Nout)
      bv = *(const bf16x8*)(BT + (size_t)gc*ldbt + k0 + sq*8);
    *(bf16x8*)&Bs[sr*40 + sq*8] = bv;
    __syncthreads();
    bf16x8 af[2], bg[2];
    #pragma unroll
    for (int m = 0; m < 2; m++) af[m] = *(bf16x8*)&As[(wr*32 + m*16 + l15)*40 + l16*8];
    #pragma unroll
    for (int n = 0; n < 2; n++) bg[n] = *(bf16x8*)&Bs[(wc*32 + n*16 + l15)*40 + l16*8];
    #pragma unroll
    for (int m = 0; m < 2; m++)
      #pragma unroll
      for (int n = 0; n < 2; n++)
        acc[m][n] = __builtin_amdgcn_mfma_f32_16x16x32_bf16(af[m], bg[n], acc[m][n], 0, 0, 0);
    __syncthreads();
  }
  #pragma unroll
  for (int m = 0; m < 2; m++){
    #pragma unroll
    for (int n = 0; n < 2; n++){
      int gcol = col0 + wc*32 + n*16 + l15;
      #pragma unroll
      for (int i = 0; i < 4; i++){
        int grow = row0 + wr*32 + m*16 + l16*4 + i;
        if (grow < M && gcol < Nout)
          C[(size_t)grow*ldc + gcol] = acc[m][n][i] + (bias ? bias[gcol] : 0.f);
      }
    }
  }
}

// ---------------- big-tile MFMA GEMM: 256 rows x full-N, 512 threads -------
template<int MREP>
__global__ __launch_bounds__(512) void k_mfma_big(int M, int K, int FI,
    const short* __restrict__ P0, const short* __restrict__ P1,
    const short* __restrict__ P2, const short* __restrict__ P3,
    const short* __restrict__ P4,
    const float* __restrict__ r1, const float* __restrict__ r2,
    const short* __restrict__ BT,
    float* __restrict__ C)
{
  constexpr int WCG = MREP/2;          // wave col groups (Nout/64)
  constexpr int NOUT = WCG*64;
  __shared__ short As[256*40];
  __shared__ short Bs[256*40];         // only NOUT*40 used
  const short* Pt[5] = {P0, P1, P2, P3, P4};
  int tid = threadIdx.x;
  int lane = tid & 63, w = tid >> 6;
  int wid_c = w % WCG, wid_r = w / WCG;
  int wrow = wid_r * (MREP*16);
  int wcol = wid_c * 64;
  int l15 = lane & 15, l16 = lane >> 4;
  int row0 = blockIdx.x*256;
  int trow = tid >> 1, tseg = tid & 1;
  f32x4 acc[MREP][4] = {};
  for (int k0 = 0; k0 < K; k0 += 32){
    int kb = k0 / FI;
    int pi = (kb == 0) ? 0 : ((kb - 1) & 3) + 1;
    int sm = (kb == 0) ? 0 : ((kb - 1) >> 2);
    const short* __restrict__ P = Pt[pi];
    int j0 = k0 - kb*FI + tseg*16;
    int gr = row0 + trow;
    bf16x8 a0 = {0,0,0,0,0,0,0,0}, a1 = a0;
    if (gr < M){
      const short* src = P + (size_t)gr*FI + j0;
      a0 = *(const bf16x8*)src;
      a1 = *(const bf16x8*)(src + 8);
      if (sm){
        float s = (sm == 1) ? r1[gr] : r2[gr];
        #pragma unroll
        for (int e = 0; e < 8; e++){ a0[e] = f2bf(bf2f(a0[e])*s); a1[e] = f2bf(bf2f(a1[e])*s); }
      }
    }
    *(bf16x8*)&As[trow*40 + tseg*16] = a0;
    *(bf16x8*)&As[trow*40 + tseg*16 + 8] = a1;
    if (trow < NOUT){
      const short* src = BT + (size_t)trow*K + k0 + tseg*16;
      *(bf16x8*)&Bs[trow*40 + tseg*16]     = *(const bf16x8*)src;
      *(bf16x8*)&Bs[trow*40 + tseg*16 + 8] = *(const bf16x8*)(src + 8);
    }
    __syncthreads();
    bf16x8 af[MREP], bg[4];
    #pragma unroll
    for (int m = 0; m < MREP; m++) af[m] = *(bf16x8*)&As[(wrow + m*16 + l15)*40 + l16*8];
    #pragma unroll
    for (int n = 0; n < 4; n++) bg[n] = *(bf16x8*)&Bs[(wcol + n*16 + l15)*40 + l16*8];
    #pragma unroll
    for (int m = 0; m < MREP; m++)
      #pragma unroll
      for (int n = 0; n < 4; n++)
        acc[m][n] = __builtin_amdgcn_mfma_f32_16x16x32_bf16(af[m], bg[n], acc[m][n], 0, 0, 0);
    __syncthreads();
  }
  #pragma unroll
  for (int m = 0; m < MREP; m++){
    #pragma unroll
    for (int n = 0; n < 4; n++){
      int gcol = wcol + n*16 + l15;
      #pragma unroll
      for (int i = 0; i < 4; i++){
        int grow = row0 + wrow + m*16 + l16*4 + i;
        if (grow < M)
          C[(size_t)grow*NOUT + gcol] = acc[m][n][i];
      }
    }
  }
}

// ---------------- MFMA aggregation v3 ----------------------
// Wave handles node n, feature slice [c0, c0+NC*16). t_d folded into MFMA via
// A k=13 == 1.0 and B row 13 := t_d[n] (bfrag[c][5] on l16==1 lanes).
// Full tiles have no masks; tail tile masks invalid slots.
template<int NC, int FI>   // FI = fi, NC*16 features per wave
__global__ __launch_bounds__(256) void k_agg3(
    const int* __restrict__ offs, const int* __restrict__ ssrc,
    const short* __restrict__ ea_s,      // [NE+16][16] bf16 CSR order, [13]=1.0
    const short* __restrict__ t_d,       // [NN][FI] bf16 (bL fused)
    const short* __restrict__ t_s,       // [NN][FI] bf16
    const short* __restrict__ WeLT,      // [FI][32] bf16, rows k>=13 zero
    short* __restrict__ mean, short* __restrict__ mn,
    short* __restrict__ mx,  short* __restrict__ stdv)
{
  constexpr int SUBS = FI / (NC*16);
  int wv = (blockIdx.x*blockDim.x + threadIdx.x) >> 6;
  int n = wv / SUBS, sub = wv - n*SUBS;
  if (n >= NN) return;
  int lane = threadIdx.x & 63;
  int l15 = lane & 15, l16 = lane >> 4;
  int c0 = sub * NC * 16;
  bool ins = (l16 == 1);
  bf16x8 bfrag[NC];
  #pragma unroll
  for (int c = 0; c < NC; c++){
    bfrag[c] = *(const bf16x8*)(WeLT + (size_t)(c0 + c*16 + l15)*32 + l16*8);
    short td = t_d[(size_t)n*FI + c0 + c*16 + l15];
    if (ins) bfrag[c][5] = td;
  }
  float s[NC], s2[NC], vmn[NC], vmx[NC];
  #pragma unroll
  for (int c = 0; c < NC; c++){ s[c]=0.f; s2[c]=0.f; vmn[c]=FLT_MAX; vmx[c]=-FLT_MAX; }
  int e0 = offs[n], e1 = offs[n+1];
  int p0 = e0;
  // ---- full tiles: no masks ----
  for (; p0 + 16 <= e1; p0 += 16){
    bf16x8 afrag = *(const bf16x8*)(ea_s + (size_t)(p0 + l15)*16 + l16*8);
    int voff[4];
    #pragma unroll
    for (int i = 0; i < 4; i++)
      voff[i] = ssrc[p0 + l16*4 + i]*FI + c0 + l15;
    #pragma unroll
    for (int c = 0; c < NC; c++){
      f32x4 acc = {0.f,0.f,0.f,0.f};
      acc = __builtin_amdgcn_mfma_f32_16x16x32_bf16(afrag, bfrag[c], acc, 0, 0, 0);
      #pragma unroll
      for (int i = 0; i < 4; i++){
        float m = acc[i] + bf2f(t_s[voff[i] + c*16]);
        s[c] += m;
        s2[c] = fmaf(m, m, s2[c]);
        vmn[c] = fminf(vmn[c], m);
        vmx[c] = fmaxf(vmx[c], m);
      }
    }
  }
  // ---- tail tile: masked ----
  if (p0 < e1){
    int pa = p0 + l15; if (pa > e1-1) pa = e1-1;
    bf16x8 afrag = *(const bf16x8*)(ea_s + (size_t)pa*16 + l16*8);
    int voff[4]; bool val[4];
    #pragma unroll
    for (int i = 0; i < 4; i++){
      int pp = p0 + l16*4 + i;
      val[i] = pp < e1;
      int pc = val[i] ? pp : (e1-1);
      voff[i] = ssrc[pc]*FI + c0 + l15;
    }
    #pragma unroll
    for (int c = 0; c < NC; c++){
      f32x4 acc = {0.f,0.f,0.f,0.f};
      acc = __builtin_amdgcn_mfma_f32_16x16x32_bf16(afrag, bfrag[c], acc, 0, 0, 0);
      #pragma unroll
      for (int i = 0; i < 4; i++){
        float m = acc[i] + bf2f(t_s[voff[i] + c*16]);
        float mv = val[i] ? m : 0.f;
        s[c] += mv;
        s2[c] = fmaf(mv, mv, s2[c]);
        vmn[c] = fminf(vmn[c], val[i] ? m :  FLT_MAX);
        vmx[c] = fmaxf(vmx[c], val[i] ? m : -FLT_MAX);
      }
    }
  }
  int cdeg = e1 - e0;
  float denom = fmaxf((float)cdeg, 1.f);
  float rden = 1.0f / denom;
  short* outp = (l16==0) ? mean : (l16==1) ? mn : (l16==2) ? mx : stdv;
  #pragma unroll
  for (int c = 0; c < NC; c++){
    float sv = s[c];   sv  += __shfl_xor(sv, 16, 64);  sv  += __shfl_xor(sv, 32, 64);
    float s2v = s2[c]; s2v += __shfl_xor(s2v, 16, 64); s2v += __shfl_xor(s2v, 32, 64);
    float mnv = vmn[c]; mnv = fminf(mnv, __shfl_xor(mnv, 16, 64)); mnv = fminf(mnv, __shfl_xor(mnv, 32, 64));
    float mxv = vmx[c]; mxv = fmaxf(mxv, __shfl_xor(mxv, 16, 64)); mxv = fmaxf(mxv, __shfl_xor(mxv, 32, 64));
    float me = sv*rden, me2 = s2v*rden;
    float sd = sqrtf(fmaxf(me2 - me*me, 0.f) + 1e-5f);
    float val = (l16==0) ? me : (l16==1) ? (cdeg>0 ? mnv : 0.f)
              : (l16==2) ? (cdeg>0 ? mxv : 0.f) : sd;
    outp[(size_t)n*FI + c0 + c*16 + l15] = f2bf(val);
  }
}

// ---------------- BatchNorm ----------------
__global__ void k_bn_reduce(const float* __restrict__ x, float* __restrict__ sums, int fo, int rows){
  __shared__ float sh[512];
  int tid = threadIdx.x;
  int col = tid % fo, grp = tid / fo, ngrp = 256 / fo;
  float s = 0.f, s2 = 0.f;
  int r0 = blockIdx.x * rows;
  int rend = min(r0 + rows, NN);
  for (int r = r0 + grp; r < rend; r += ngrp){
    float v = x[(size_t)r*fo + col];
    s += v; s2 += v*v;
  }
  sh[tid] = s; sh[256 + tid] = s2;
  __syncthreads();
  if (grp == 0){
    for (int g = 1; g < ngrp; g++){ s += sh[g*fo + col]; s2 += sh[256 + g*fo + col]; }
    atomicAdd(&sums[col], s);
    atomicAdd(&sums[fo + col], s2);
  }
}

__global__ void k_bn_apply(const float* __restrict__ x, const float* __restrict__ sums,
                           const float* __restrict__ g, const float* __restrict__ b,
                           short* __restrict__ xbf, int fo, int total){
  int i = blockIdx.x*blockDim.x + threadIdx.x;
  if (i >= total) return;
  int col = i % fo;
  float mu = sums[col] / (float)NN;
  float var = sums[fo + col] / (float)NN - mu*mu;
  float v = (x[i] - mu) * rsqrtf(var + 1e-5f) * g[col] + b[col];
  xbf[i] = f2bf(fmaxf(v, 0.f));
}

// ---------------- host ----------------
extern "C" void kernel_launch(void* const* d_in, const int* in_sizes, int n_in,
                              void* d_out, int out_size, void* d_ws, size_t ws_size,
                              hipStream_t stream){
  const float* x0 = (const float*)d_in[0];
  const int*   ei = (const int*)d_in[1];
  const float* ea = (const float*)d_in[2];
  const float* W[35];
  for (int i = 0; i < 35; i++) W[i] = (const float*)d_in[i];
  const float* wc = W[33];
  const float* bc = W[34];

  char* w = (char*)d_ws;
  auto alloc = [&](size_t bytes)->void*{
    void* p = (void*)w; w += (bytes + 255) & ~(size_t)255; return p;
  };
  int* cnt    = (int*)alloc((size_t)NN*4);
  int* offs   = (int*)alloc((size_t)(NN+1)*4);
  int* cursor = (int*)alloc((size_t)NN*4);
  int* totals = (int*)alloc(64*4);
  int* ssrc   = (int*)alloc((size_t)NE*4);
  int* seid   = (int*)alloc((size_t)NE*4);
  float* sumlog = (float*)alloc(256);
  float* r1   = (float*)alloc((size_t)NN*4);
  float* r2   = (float*)alloc((size_t)NN*4);
  float* bns  = (float*)alloc(512*4);
  float* bL   = (float*)alloc(128*4);
  short* WeLT = (short*)alloc((size_t)128*32*2);
  short* WolT = (short*)alloc((size_t)256*1664*2);
  short* wpT  = (short*)alloc((size_t)2*128*128*2);
  short* wcT  = (short*)alloc((size_t)10*256*2);
  short* ea_s = (short*)alloc((size_t)(NE+16)*16*2);  // bf16, CSR-permuted, padded
  short* agg[4];
  for (int a = 0; a < 4; a++) agg[a] = (short*)alloc((size_t)NN*128*2);
  float* F    = (float*)alloc((size_t)NN*256*4);      // z-out fp32; t_d/t_s bf16 alias
  short* xbfA = (short*)alloc((size_t)NN*128*2);
  short* xbfB = (short*)alloc((size_t)NN*256*2);

  hipMemsetAsync(cnt, 0, (size_t)NN*4, stream);
  hipMemsetAsync(sumlog, 0, 4, stream);
  k_count<<<(NE+255)/256, 256, 0, stream>>>(ei + NE, cnt);
  k_scan_part<<<49, 1024, 0, stream>>>(cnt, offs, totals);
  k_scan_tops<<<1, 64, 0, stream>>>(totals, 49);
  k_scan_add<<<(NN+256)/256, 256, 0, stream>>>(offs, totals, cursor);
  k_scatter<<<(NE+255)/256, 256, 0, stream>>>(ei, cursor, ssrc, seid);
  k_permute_ea<<<(NE*16+255)/256, 256, 0, stream>>>(ea, seid, ea_s);
  k_sumlog<<<256, 256, 0, stream>>>(cnt, sumlog);
  k_rscale<<<(NN+255)/256, 256, 0, stream>>>(cnt, sumlog, r1, r2);
  k_prep_wcT<<<10, 256, 0, stream>>>(wc, wcT);
  k_f2bf_arr<<<(NN*32+255)/256, 256, 0, stream>>>(x0, xbfA, NN*32);

  const short* xin = xbfA;
  const int fis[3] = {32, 64, 128};
  const int GX = (NN + 63) / 64;
  const int GB = (NN + 255) / 256;
  for (int l = 0; l < 3; l++){
    int fi = fis[l], fo = 2*fi;
    const float* we = W[3+10*l+0], *be = W[3+10*l+1];
    const float* wp = W[3+10*l+2], *bp = W[3+10*l+3];
    const float* wo = W[3+10*l+4];
    const float* wl = W[3+10*l+6];
    const float* g  = W[3+10*l+8], *bb = W[3+10*l+9];

    short* t_d = (short*)F;                  // [NN, fi] bf16 — dead before F rewritten
    short* t_s = (short*)F + (size_t)NN*fi;  // [NN, fi] bf16

    k_prep_welt<<<(fi*32+255)/256, 256, 0, stream>>>(we, wp, WeLT, fi);
    k_prep_bl<<<(fi+127)/128, 128, 0, stream>>>(be, wp, bp, bL, fi);
    k_prep_wolT<<<13*fi, fo, 0, stream>>>(wo, wl, WolT, fo, 13*fi);
    k_prep_wpT<<<(2*fi*fi+255)/256, 256, 0, stream>>>(wp, wpT, fi);

    dim3 gt(GX, (fi + 63) / 64);
    k_gemm_t<<<gt, 256, 0, stream>>>(NN, fi, fi, xin, wpT, bL, t_d);
    k_gemm_t<<<gt, 256, 0, stream>>>(NN, fi, fi, xin, wpT + (size_t)fi*fi, nullptr, t_s);

    if (l == 0){
      int GA3 = (NN*64 + 255)/256;          // 1 wave/node
      k_agg3<2,32><<<GA3, 256, 0, stream>>>(offs, ssrc, ea_s, t_d, t_s, WeLT,
          agg[0], agg[1], agg[2], agg[3]);
    } else if (l == 1){
      int GA3 = (NN*64 + 255)/256;          // 1 wave/node
      k_agg3<4,64><<<GA3, 256, 0, stream>>>(offs, ssrc, ea_s, t_d, t_s, WeLT,
          agg[0], agg[1], agg[2], agg[3]);
    } else {
      int GA3 = (NN*2*64 + 255)/256;        // 2 waves/node
      k_agg3<4,128><<<GA3, 256, 0, stream>>>(offs, ssrc, ea_s, t_d, t_s, WeLT,
          agg[0], agg[1], agg[2], agg[3]);
    }

    if (l == 0)
      k_mfma_big<2><<<GB, 512, 0, stream>>>(NN, 13*fi, fi, xin, agg[0], agg[1], agg[2], agg[3],
          r1, r2, WolT, F);
    else if (l == 1)
      k_mfma_big<4><<<GB, 512, 0, stream>>>(NN, 13*fi, fi, xin, agg[0], agg[1], agg[2], agg[3],
          r1, r2, WolT, F);
    else
      k_mfma_big<8><<<GB, 512, 0, stream>>>(NN, 13*fi, fi, xin, agg[0], agg[1], agg[2], agg[3],
          r1, r2, WolT, F);

    short* xbf_next = (l == 0) ? xbfB : ((l == 1) ? xbfA : xbfB);
    hipMemsetAsync(bns, 0, (size_t)2*fo*4, stream);
    k_bn_reduce<<<256, 256, 0, stream>>>(F, bns, fo, (NN+255)/256);
    k_bn_apply<<<((NN*fo)+255)/256, 256, 0, stream>>>(F, bns, g, bb, xbf_next, fo, NN*fo);

    xin = xbf_next;
  }

  dim3 gc(GX, 1);
  k_mfma<<<gc, 256, 0, stream>>>(NN, 10, 256, xin, wcT, 256, (float*)d_out, 10, bc);
}